// Round 3
// baseline (18927.437 us; speedup 1.0000x reference)
//
#include <hip/hip_runtime.h>
#include <hip/hip_bf16.h>

#define NNODES 50000
#define TSTEPS 8
#define NEDGES 800000
#define VVOCAB 1000
#define DDIM 32
#define HDIM 128
#define G0DIM 64
#define H3 384

// ---------------- zero fill (float4) ----------------------------------------------------
__global__ __launch_bounds__(256) void fill_zero4(float4* __restrict__ p, long long n4) {
  long long i = (long long)blockIdx.x * 256 + threadIdx.x;
  long long stride = (long long)gridDim.x * 256;
  float4 z = {0.f, 0.f, 0.f, 0.f};
  for (; i < n4; i += stride) p[i] = z;
}

// ---- fused weight precompute: Wf[t] = W2_t @ Wx  ([128,128]@[128,384]) -------------------
__global__ __launch_bounds__(384) void fuse_w(
    const float* __restrict__ gW2, const float* __restrict__ Wx, float* __restrict__ Wf) {
  int t = blockIdx.x >> 7;
  int k = blockIdx.x & 127;
  int j = threadIdx.x;
  __shared__ float row[HDIM];
  if (j < HDIM) row[j] = gW2[((size_t)t * HDIM + k) * HDIM + j];
  __syncthreads();
  float acc = 0.f;
#pragma unroll 8
  for (int c = 0; c < HDIM; ++c) acc += row[c] * Wx[c * H3 + j];
  Wf[((size_t)t * HDIM + k) * H3 + j] = acc;
}

// ---- fused bias precompute: bf[t] = b2_t @ Wx + bx ---------------------------------------
__global__ __launch_bounds__(384) void fuse_b(
    const float* __restrict__ gb2, const float* __restrict__ Wx,
    const float* __restrict__ bx, float* __restrict__ bf) {
  int t = blockIdx.x;
  int j = threadIdx.x;
  __shared__ float row[HDIM];
  if (j < HDIM) row[j] = gb2[t * HDIM + j];
  __syncthreads();
  float acc = bx[j];
#pragma unroll 8
  for (int c = 0; c < HDIM; ++c) acc += row[c] * Wx[c * H3 + j];
  bf[t * H3 + j] = acc;
}

// ---- static encoder + attention init: acc=se, mx=logit(se), s=1 ------------------------
__global__ __launch_bounds__(128) void static_encode_attn_init(
    const float* __restrict__ dense, const int* __restrict__ sparse,
    const float* __restrict__ emb,   // (2,V,16)
    const float* __restrict__ Ws, const float* __restrict__ bs,
    const float* __restrict__ Waw, const float* __restrict__ baw,
    float* __restrict__ acc, float* __restrict__ s, float* __restrict__ mx) {
  int n = blockIdx.x;
  int j = threadIdx.x; // 0..127
  __shared__ float xs[G0DIM];
  if (j < G0DIM) {
    float v;
    if (j < 16) {
      v = emb[sparse[n * 2 + 0] * 16 + j];
    } else if (j < 32) {
      v = emb[VVOCAB * 16 + sparse[n * 2 + 1] * 16 + (j - 16)];
    } else {
      v = dense[n * DDIM + (j - 32)];
    }
    xs[j] = v;
  }
  __syncthreads();
  float a = bs[j];
#pragma unroll 16
  for (int k = 0; k < G0DIM; ++k) a += xs[k] * Ws[k * HDIM + j];
  a = fmaxf(a, 0.f);
  float v = tanhf(a) * Waw[j];
  __shared__ float red[2];
  int lane = j & 63, wid = j >> 6;
#pragma unroll
  for (int off = 32; off > 0; off >>= 1) v += __shfl_down(v, off, 64);
  if (lane == 0) red[wid] = v;
  __syncthreads();
  acc[(size_t)n * HDIM + j] = a;  // weight exp(l-m)=1 since m=l
  if (j == 0) {
    s[n] = 1.f;
    mx[n] = red[0] + red[1] + baw[0];
  }
}

// ---------------- dynamic feature gather, float4 per thread ------------------------------
__global__ __launch_bounds__(256) void dynx_gather4(
    const float* __restrict__ dense_t, const int* __restrict__ sparse_t,
    const float* __restrict__ emb, float4* __restrict__ xout) {
  int idx = blockIdx.x * 256 + threadIdx.x;  // over N*16
  int n = idx >> 4, k4 = idx & 15;
  if (n >= NNODES) return;
  float4 v;
  if (k4 < 4)
    v = *(const float4*)&emb[sparse_t[n * 2 + 0] * 16 + k4 * 4];
  else if (k4 < 8)
    v = *(const float4*)&emb[VVOCAB * 16 + sparse_t[n * 2 + 1] * 16 + (k4 - 4) * 4];
  else
    v = *(const float4*)&dense_t[n * DDIM + (k4 - 8) * 4];
  xout[idx] = v;
}

// ---------------- segment_sum via atomics, float4 per thread -----------------------------
template <int D>
__global__ __launch_bounds__(256) void scatter_add4(
    const int* __restrict__ e_src, const int* __restrict__ e_dst,
    const float* __restrict__ w, const float* __restrict__ x,
    float* __restrict__ m) {
  const int G = D / 4;
  long long idx = (long long)blockIdx.x * 256 + threadIdx.x;
  int e = (int)(idx / G);
  int k4 = (int)(idx & (G - 1));
  if (e >= NEDGES) return;
  int sidx = e_src[e];
  int d = e_dst[e];
  float wv = w[e];
  float4 xv = *(const float4*)&x[(size_t)sidx * D + k4 * 4];
  float* mp = &m[(size_t)d * D + k4 * 4];
  atomicAdd(mp + 0, wv * xv.x);
  atomicAdd(mp + 1, wv * xv.y);
  atomicAdd(mp + 2, wv * xv.z);
  atomicAdd(mp + 3, wv * xv.w);
}

// ---------------- row matmul, transposed-LDS float4: y = (relu?)(x@W + b) ----------------
// x: [nrows,K], W: [K,NCOL], block = NCOL threads, NB rows per block (NB==8)
template <int K, int NCOL, bool RELU>
__global__ __launch_bounds__(NCOL) void rowmm_t(
    const float* __restrict__ x, const float* __restrict__ W,
    const float* __restrict__ b, float* __restrict__ y, int nrows) {
  const int NB = 8;
  int n0 = blockIdx.x * NB;
  int j = threadIdx.x;
  __shared__ float xT[K][12];  // [k][q], pad 12 for 16B-aligned float4 + bank spread
  for (int i = j; i < NB * K; i += NCOL) {
    int q = i / K, k = i % K;
    xT[k][q] = (n0 + q < nrows) ? x[(size_t)(n0 + q) * K + k] : 0.f;
  }
  __syncthreads();
  float acc0 = 0.f, acc1 = 0.f, acc2 = 0.f, acc3 = 0.f;
  float acc4 = 0.f, acc5 = 0.f, acc6 = 0.f, acc7 = 0.f;
  for (int k = 0; k < K; ++k) {
    float wv = W[(size_t)k * NCOL + j];
    float4 a = *(const float4*)&xT[k][0];
    float4 c = *(const float4*)&xT[k][4];
    acc0 += a.x * wv; acc1 += a.y * wv; acc2 += a.z * wv; acc3 += a.w * wv;
    acc4 += c.x * wv; acc5 += c.y * wv; acc6 += c.z * wv; acc7 += c.w * wv;
  }
  float bj = b[j];
  float accs[NB] = {acc0, acc1, acc2, acc3, acc4, acc5, acc6, acc7};
#pragma unroll
  for (int q = 0; q < NB; ++q) {
    if (n0 + q < nrows) {
      float v = accs[q] + bj;
      y[(size_t)(n0 + q) * NCOL + j] = RELU ? fmaxf(v, 0.f) : v;
    }
  }
}

// ---------------- fused GRU step + online-softmax attention update -----------------------
// gx = m2 @ Wf + bf (fused W2*Wx), gh = hprev @ Wh + bh, GRU elementwise, attn update.
__global__ __launch_bounds__(384) void gru_fused(
    const float* __restrict__ m2, const float* __restrict__ hprev,
    const float* __restrict__ Wf, const float* __restrict__ Wh,
    const float* __restrict__ bf, const float* __restrict__ bh,
    const float* __restrict__ Waw, const float* __restrict__ baw,
    float* __restrict__ hout, float* __restrict__ acc,
    float* __restrict__ sden, float* __restrict__ mxv, int nrows) {
  const int NB = 8;
  int n0 = blockIdx.x * NB;
  int j = threadIdx.x;  // 0..383
  __shared__ float xT[HDIM][12];  // m2 transposed
  __shared__ float hT[HDIM][12];  // hprev transposed
  __shared__ float sx[NB][H3], sh[NB][H3];
  __shared__ float red[NB][2];
  __shared__ float facs[NB], ps[NB];

  for (int i = j; i < NB * HDIM; i += 384) {
    int q = i >> 7, k = i & 127;
    int n = n0 + q;
    xT[k][q] = (n < nrows) ? m2[(size_t)n * HDIM + k] : 0.f;
    hT[k][q] = (n < nrows && hprev) ? hprev[(size_t)n * HDIM + k] : 0.f;
  }
  __syncthreads();

  float ax0 = 0.f, ax1 = 0.f, ax2 = 0.f, ax3 = 0.f, ax4 = 0.f, ax5 = 0.f, ax6 = 0.f, ax7 = 0.f;
  float ah0 = 0.f, ah1 = 0.f, ah2 = 0.f, ah3 = 0.f, ah4 = 0.f, ah5 = 0.f, ah6 = 0.f, ah7 = 0.f;
  for (int k = 0; k < HDIM; ++k) {
    float wf = Wf[(size_t)k * H3 + j];
    float wh = Wh[(size_t)k * H3 + j];
    float4 a = *(const float4*)&xT[k][0];
    float4 c = *(const float4*)&xT[k][4];
    float4 e = *(const float4*)&hT[k][0];
    float4 f = *(const float4*)&hT[k][4];
    ax0 += a.x * wf; ax1 += a.y * wf; ax2 += a.z * wf; ax3 += a.w * wf;
    ax4 += c.x * wf; ax5 += c.y * wf; ax6 += c.z * wf; ax7 += c.w * wf;
    ah0 += e.x * wh; ah1 += e.y * wh; ah2 += e.z * wh; ah3 += e.w * wh;
    ah4 += f.x * wh; ah5 += f.y * wh; ah6 += f.z * wh; ah7 += f.w * wh;
  }
  float bfj = bf[j], bhj = bh[j];
  {
    float axs[NB] = {ax0, ax1, ax2, ax3, ax4, ax5, ax6, ax7};
    float ahs[NB] = {ah0, ah1, ah2, ah3, ah4, ah5, ah6, ah7};
#pragma unroll
    for (int q = 0; q < NB; ++q) {
      sx[q][j] = axs[q] + bfj;
      sh[q][j] = ahs[q] + bhj;
    }
  }
  __syncthreads();

  float hn[NB];
  if (j < HDIM) {
    float waw = Waw[j];
    int lane = j & 63, wid = j >> 6;
#pragma unroll
    for (int q = 0; q < NB; ++q) {
      float r = 1.f / (1.f + expf(-(sx[q][j] + sh[q][j])));
      float z = 1.f / (1.f + expf(-(sx[q][j + 128] + sh[q][j + 128])));
      float nc = tanhf(sx[q][j + 256] + r * sh[q][j + 256]);
      float hprev_v = hT[j][q];
      float hv = (1.f - z) * nc + z * hprev_v;
      hn[q] = hv;
      if (n0 + q < nrows) hout[(size_t)(n0 + q) * HDIM + j] = hv;
      float v = tanhf(hv) * waw;
#pragma unroll
      for (int off = 32; off > 0; off >>= 1) v += __shfl_down(v, off, 64);
      if (lane == 0) red[q][wid] = v;
    }
  }
  __syncthreads();
  if (j < NB) {
    int n = n0 + j;
    if (n < nrows) {
      float l = red[j][0] + red[j][1] + baw[0];
      float m = mxv[n];
      float mnew = fmaxf(m, l);
      float fac = expf(m - mnew);
      float p = expf(l - mnew);
      facs[j] = fac;
      ps[j] = p;
      sden[n] = sden[n] * fac + p;
      mxv[n] = mnew;
    }
  }
  __syncthreads();
  if (j < HDIM) {
#pragma unroll
    for (int q = 0; q < NB; ++q) {
      int n = n0 + q;
      if (n < nrows) {
        size_t off = (size_t)n * HDIM + j;
        acc[off] = acc[off] * facs[q] + ps[q] * hn[q];
      }
    }
  }
}

// ---- finalize: out /= s ------------------------------------------------------------------
__global__ __launch_bounds__(256) void attn_finalize(
    float* __restrict__ acc, const float* __restrict__ s) {
  int idx = blockIdx.x * 256 + threadIdx.x;
  if (idx >= NNODES * HDIM) return;
  acc[idx] = acc[idx] / s[idx >> 7];
}

extern "C" void kernel_launch(void* const* d_in, const int* in_sizes, int n_in,
                              void* d_out, int out_size, void* d_ws, size_t ws_size,
                              hipStream_t stream) {
  const float* static_dense = (const float*)d_in[0];
  const int*   static_sparse = (const int*)d_in[1];
  const float* dyn_dense = (const float*)d_in[2];
  const int*   dyn_sparse = (const int*)d_in[3];
  const int*   edges = (const int*)d_in[4];
  const float* weights = (const float*)d_in[5];
  const float* s_emb = (const float*)d_in[6];
  const float* d_emb = (const float*)d_in[7];
  const float* Ws = (const float*)d_in[8];
  const float* bs = (const float*)d_in[9];
  const float* gW1 = (const float*)d_in[10];
  const float* gb1 = (const float*)d_in[11];
  const float* gW2 = (const float*)d_in[12];
  const float* gb2 = (const float*)d_in[13];
  const float* Wx = (const float*)d_in[14];
  const float* Wh = (const float*)d_in[15];
  const float* bx = (const float*)d_in[16];
  const float* bh = (const float*)d_in[17];
  const float* Waw = (const float*)d_in[18];
  const float* baw = (const float*)d_in[19];
  float* out = (float*)d_out;  // attention accumulator [N,128]

  const size_t N = NNODES;
  float* ws = (float*)d_ws;
  float* sden = ws;                    // N
  float* mxv  = sden + N;              // N
  float* hA   = mxv + N;               // N*128
  float* hB   = hA + N * HDIM;         // N*128
  float* R1   = hB + N * HDIM;         // N*128: dynx(N*64)|m1(N*64), then m2(N*128)
  float* h1   = R1 + N * HDIM;         // N*128
  float* Wf   = h1 + N * HDIM;         // 8*128*384
  float* bfb  = Wf + (size_t)TSTEPS * HDIM * H3;  // 8*384
  float* dynx = R1;
  float* m1   = R1 + N * G0DIM;
  float* m2   = R1;

  fuse_w<<<TSTEPS * HDIM, H3, 0, stream>>>(gW2, Wx, Wf);
  fuse_b<<<TSTEPS, H3, 0, stream>>>(gb2, Wx, bx, bfb);

  static_encode_attn_init<<<NNODES, 128, 0, stream>>>(
      static_dense, static_sparse, s_emb, Ws, bs, Waw, baw, out, sden, mxv);

  for (int t = 0; t < TSTEPS; ++t) {
    const int* e_src = edges + (size_t)t * 2 * NEDGES;
    const int* e_dst = e_src + NEDGES;
    const float* w_t = weights + (size_t)t * NEDGES;
    float* hcur = (t & 1) ? hB : hA;
    const float* hprev = (t == 0) ? nullptr : ((t & 1) ? hA : hB);

    dynx_gather4<<<(NNODES * 16 + 255) / 256, 256, 0, stream>>>(
        dyn_dense + (size_t)t * N * DDIM, dyn_sparse + (size_t)t * N * 2, d_emb,
        (float4*)dynx);

    fill_zero4<<<1024, 256, 0, stream>>>((float4*)m1, (long long)N * G0DIM / 4);
    {
      long long total = (long long)NEDGES * (G0DIM / 4);
      scatter_add4<G0DIM><<<(int)((total + 255) / 256), 256, 0, stream>>>(
          e_src, e_dst, w_t, dynx, m1);
    }
    rowmm_t<G0DIM, HDIM, true><<<(NNODES + 7) / 8, HDIM, 0, stream>>>(
        m1, gW1 + (size_t)t * G0DIM * HDIM, gb1 + (size_t)t * HDIM, h1, NNODES);

    fill_zero4<<<1024, 256, 0, stream>>>((float4*)m2, (long long)N * HDIM / 4);
    {
      long long total = (long long)NEDGES * (HDIM / 4);
      scatter_add4<HDIM><<<(int)((total + 255) / 256), 256, 0, stream>>>(
          e_src, e_dst, w_t, h1, m2);
    }

    gru_fused<<<(NNODES + 7) / 8, 384, 0, stream>>>(
        m2, hprev, Wf + (size_t)t * HDIM * H3, Wh, bfb + t * H3, bh,
        Waw, baw, hcur, out, sden, mxv, NNODES);
  }

  attn_finalize<<<(NNODES * HDIM + 255) / 256, 256, 0, stream>>>(out, sden);
}

// Round 4
// 5602.267 us; speedup vs baseline: 3.3785x; 3.3785x over previous
//
#include <hip/hip_runtime.h>
#include <hip/hip_bf16.h>

#define NNODES 50000
#define TSTEPS 8
#define NEDGES 800000
#define VVOCAB 1000
#define DDIM 32
#define HDIM 128
#define G0DIM 64
#define H3 384

// ---------------- zero fill for int counters ---------------------------------------------
__global__ __launch_bounds__(256) void fill_zero_int(int* __restrict__ p, int n) {
  int i = blockIdx.x * 256 + threadIdx.x;
  if (i < n) p[i] = 0;
}

// ---------------- CSR build: histogram ----------------------------------------------------
__global__ __launch_bounds__(256) void hist_dst(const int* __restrict__ e_dst,
                                                int* __restrict__ deg) {
  int e = blockIdx.x * 256 + threadIdx.x;
  if (e < NEDGES) atomicAdd(&deg[e_dst[e]], 1);
}

// ---------------- CSR build: single-block scan (off = exclusive prefix, off[N]=E) ---------
__global__ __launch_bounds__(1024) void scan_deg(const int* __restrict__ deg,
                                                 int* __restrict__ off,
                                                 int* __restrict__ cursor) {
  const int T = 1024;
  const int CH = (NNODES + T - 1) / T;  // 49
  int t = threadIdx.x;
  int start = t * CH;
  int end = min(start + CH, NNODES);
  __shared__ int buf[T];
  int s = 0;
  for (int i = start; i < end; ++i) s += deg[i];
  buf[t] = s;
  __syncthreads();
  for (int d = 1; d < T; d <<= 1) {
    int v = (t >= d) ? buf[t - d] : 0;
    __syncthreads();
    buf[t] += v;
    __syncthreads();
  }
  int pre = (t == 0) ? 0 : buf[t - 1];
  for (int i = start; i < end; ++i) {
    off[i] = pre;
    cursor[i] = pre;
    pre += deg[i];
  }
  if (t == T - 1) off[NNODES] = buf[T - 1];
}

// ---------------- CSR build: bucket fill ---------------------------------------------------
__global__ __launch_bounds__(256) void fill_csr(
    const int* __restrict__ e_src, const int* __restrict__ e_dst,
    const float* __restrict__ w, int* __restrict__ cursor,
    int* __restrict__ csr_src, float* __restrict__ csr_w) {
  int e = blockIdx.x * 256 + threadIdx.x;
  if (e >= NEDGES) return;
  int d = e_dst[e];
  int pos = atomicAdd(&cursor[d], 1);
  csr_src[pos] = e_src[e];
  csr_w[pos] = w[e];
}

// ---------------- pull aggregation: m[n,:] = sum_e w_e * x[src_e,:] -----------------------
template <int D>
__global__ __launch_bounds__(256) void gather_agg(
    const int* __restrict__ off, const int* __restrict__ csr_src,
    const float* __restrict__ csr_w, const float* __restrict__ x,
    float* __restrict__ m) {
  const int NPB = 256 / D;
  int n = blockIdx.x * NPB + (threadIdx.x / D);
  int j = threadIdx.x & (D - 1);
  if (n >= NNODES) return;
  int s0 = off[n], s1 = off[n + 1];
  float acc0 = 0.f, acc1 = 0.f;
  int e = s0;
  for (; e + 1 < s1; e += 2) {
    int sA = csr_src[e], sB = csr_src[e + 1];
    float wA = csr_w[e], wB = csr_w[e + 1];
    acc0 += wA * x[(size_t)sA * D + j];
    acc1 += wB * x[(size_t)sB * D + j];
  }
  if (e < s1) acc0 += csr_w[e] * x[(size_t)csr_src[e] * D + j];
  m[(size_t)n * D + j] = acc0 + acc1;
}

// ---- fused weight precompute: Wf[t] = W2_t @ Wx  ([128,128]@[128,384]) -------------------
__global__ __launch_bounds__(384) void fuse_w(
    const float* __restrict__ gW2, const float* __restrict__ Wx, float* __restrict__ Wf) {
  int t = blockIdx.x >> 7;
  int k = blockIdx.x & 127;
  int j = threadIdx.x;
  __shared__ float row[HDIM];
  if (j < HDIM) row[j] = gW2[((size_t)t * HDIM + k) * HDIM + j];
  __syncthreads();
  float acc = 0.f;
#pragma unroll 8
  for (int c = 0; c < HDIM; ++c) acc += row[c] * Wx[c * H3 + j];
  Wf[((size_t)t * HDIM + k) * H3 + j] = acc;
}

// ---- fused bias precompute: bf[t] = b2_t @ Wx + bx ---------------------------------------
__global__ __launch_bounds__(384) void fuse_b(
    const float* __restrict__ gb2, const float* __restrict__ Wx,
    const float* __restrict__ bx, float* __restrict__ bf) {
  int t = blockIdx.x;
  int j = threadIdx.x;
  __shared__ float row[HDIM];
  if (j < HDIM) row[j] = gb2[t * HDIM + j];
  __syncthreads();
  float acc = bx[j];
#pragma unroll 8
  for (int c = 0; c < HDIM; ++c) acc += row[c] * Wx[c * H3 + j];
  bf[t * H3 + j] = acc;
}

// ---- static encoder + attention init: acc=se, mx=logit(se), s=1 ------------------------
__global__ __launch_bounds__(128) void static_encode_attn_init(
    const float* __restrict__ dense, const int* __restrict__ sparse,
    const float* __restrict__ emb,   // (2,V,16)
    const float* __restrict__ Ws, const float* __restrict__ bs,
    const float* __restrict__ Waw, const float* __restrict__ baw,
    float* __restrict__ acc, float* __restrict__ s, float* __restrict__ mx) {
  int n = blockIdx.x;
  int j = threadIdx.x; // 0..127
  __shared__ float xs[G0DIM];
  if (j < G0DIM) {
    float v;
    if (j < 16) {
      v = emb[sparse[n * 2 + 0] * 16 + j];
    } else if (j < 32) {
      v = emb[VVOCAB * 16 + sparse[n * 2 + 1] * 16 + (j - 16)];
    } else {
      v = dense[n * DDIM + (j - 32)];
    }
    xs[j] = v;
  }
  __syncthreads();
  float a = bs[j];
#pragma unroll 16
  for (int k = 0; k < G0DIM; ++k) a += xs[k] * Ws[k * HDIM + j];
  a = fmaxf(a, 0.f);
  float v = tanhf(a) * Waw[j];
  __shared__ float red[2];
  int lane = j & 63, wid = j >> 6;
#pragma unroll
  for (int off = 32; off > 0; off >>= 1) v += __shfl_down(v, off, 64);
  if (lane == 0) red[wid] = v;
  __syncthreads();
  acc[(size_t)n * HDIM + j] = a;  // weight exp(l-m)=1 since m=l
  if (j == 0) {
    s[n] = 1.f;
    mx[n] = red[0] + red[1] + baw[0];
  }
}

// ---------------- dynamic feature gather, float4 per thread ------------------------------
__global__ __launch_bounds__(256) void dynx_gather4(
    const float* __restrict__ dense_t, const int* __restrict__ sparse_t,
    const float* __restrict__ emb, float4* __restrict__ xout) {
  int idx = blockIdx.x * 256 + threadIdx.x;  // over N*16
  int n = idx >> 4, k4 = idx & 15;
  if (n >= NNODES) return;
  float4 v;
  if (k4 < 4)
    v = *(const float4*)&emb[sparse_t[n * 2 + 0] * 16 + k4 * 4];
  else if (k4 < 8)
    v = *(const float4*)&emb[VVOCAB * 16 + sparse_t[n * 2 + 1] * 16 + (k4 - 4) * 4];
  else
    v = *(const float4*)&dense_t[n * DDIM + (k4 - 8) * 4];
  xout[idx] = v;
}

// ---------------- row matmul, transposed-LDS float4: y = (relu?)(x@W + b) ----------------
template <int K, int NCOL, bool RELU>
__global__ __launch_bounds__(NCOL) void rowmm_t(
    const float* __restrict__ x, const float* __restrict__ W,
    const float* __restrict__ b, float* __restrict__ y, int nrows) {
  const int NB = 8;
  int n0 = blockIdx.x * NB;
  int j = threadIdx.x;
  __shared__ float xT[K][12];  // [k][q], pad 12 -> 48B rows stay 16B-aligned
  for (int i = j; i < NB * K; i += NCOL) {
    int q = i / K, k = i % K;
    xT[k][q] = (n0 + q < nrows) ? x[(size_t)(n0 + q) * K + k] : 0.f;
  }
  __syncthreads();
  float acc0 = 0.f, acc1 = 0.f, acc2 = 0.f, acc3 = 0.f;
  float acc4 = 0.f, acc5 = 0.f, acc6 = 0.f, acc7 = 0.f;
  for (int k = 0; k < K; ++k) {
    float wv = W[(size_t)k * NCOL + j];
    float4 a = *(const float4*)&xT[k][0];
    float4 c = *(const float4*)&xT[k][4];
    acc0 += a.x * wv; acc1 += a.y * wv; acc2 += a.z * wv; acc3 += a.w * wv;
    acc4 += c.x * wv; acc5 += c.y * wv; acc6 += c.z * wv; acc7 += c.w * wv;
  }
  float bj = b[j];
  float accs[NB] = {acc0, acc1, acc2, acc3, acc4, acc5, acc6, acc7};
#pragma unroll
  for (int q = 0; q < NB; ++q) {
    if (n0 + q < nrows) {
      float v = accs[q] + bj;
      y[(size_t)(n0 + q) * NCOL + j] = RELU ? fmaxf(v, 0.f) : v;
    }
  }
}

// ---------------- fused GRU step + online-softmax attention update -----------------------
__global__ __launch_bounds__(384) void gru_fused(
    const float* __restrict__ m2, const float* __restrict__ hprev,
    const float* __restrict__ Wf, const float* __restrict__ Wh,
    const float* __restrict__ bf, const float* __restrict__ bh,
    const float* __restrict__ Waw, const float* __restrict__ baw,
    float* __restrict__ hout, float* __restrict__ acc,
    float* __restrict__ sden, float* __restrict__ mxv, int nrows) {
  const int NB = 8;
  int n0 = blockIdx.x * NB;
  int j = threadIdx.x;  // 0..383
  __shared__ float xT[HDIM][12];
  __shared__ float hT[HDIM][12];
  __shared__ float sx[NB][H3], sh[NB][H3];
  __shared__ float red[NB][2];
  __shared__ float facs[NB], ps[NB];

  for (int i = j; i < NB * HDIM; i += 384) {
    int q = i >> 7, k = i & 127;
    int n = n0 + q;
    xT[k][q] = (n < nrows) ? m2[(size_t)n * HDIM + k] : 0.f;
    hT[k][q] = (n < nrows && hprev) ? hprev[(size_t)n * HDIM + k] : 0.f;
  }
  __syncthreads();

  float ax0 = 0.f, ax1 = 0.f, ax2 = 0.f, ax3 = 0.f, ax4 = 0.f, ax5 = 0.f, ax6 = 0.f, ax7 = 0.f;
  float ah0 = 0.f, ah1 = 0.f, ah2 = 0.f, ah3 = 0.f, ah4 = 0.f, ah5 = 0.f, ah6 = 0.f, ah7 = 0.f;
  for (int k = 0; k < HDIM; ++k) {
    float wf = Wf[(size_t)k * H3 + j];
    float wh = Wh[(size_t)k * H3 + j];
    float4 a = *(const float4*)&xT[k][0];
    float4 c = *(const float4*)&xT[k][4];
    float4 e = *(const float4*)&hT[k][0];
    float4 f = *(const float4*)&hT[k][4];
    ax0 += a.x * wf; ax1 += a.y * wf; ax2 += a.z * wf; ax3 += a.w * wf;
    ax4 += c.x * wf; ax5 += c.y * wf; ax6 += c.z * wf; ax7 += c.w * wf;
    ah0 += e.x * wh; ah1 += e.y * wh; ah2 += e.z * wh; ah3 += e.w * wh;
    ah4 += f.x * wh; ah5 += f.y * wh; ah6 += f.z * wh; ah7 += f.w * wh;
  }
  float bfj = bf[j], bhj = bh[j];
  {
    float axs[NB] = {ax0, ax1, ax2, ax3, ax4, ax5, ax6, ax7};
    float ahs[NB] = {ah0, ah1, ah2, ah3, ah4, ah5, ah6, ah7};
#pragma unroll
    for (int q = 0; q < NB; ++q) {
      sx[q][j] = axs[q] + bfj;
      sh[q][j] = ahs[q] + bhj;
    }
  }
  __syncthreads();

  float hn[NB];
  if (j < HDIM) {
    float waw = Waw[j];
    int lane = j & 63, wid = j >> 6;
#pragma unroll
    for (int q = 0; q < NB; ++q) {
      float r = 1.f / (1.f + expf(-(sx[q][j] + sh[q][j])));
      float z = 1.f / (1.f + expf(-(sx[q][j + 128] + sh[q][j + 128])));
      float nc = tanhf(sx[q][j + 256] + r * sh[q][j + 256]);
      float hprev_v = hT[j][q];
      float hv = (1.f - z) * nc + z * hprev_v;
      hn[q] = hv;
      if (n0 + q < nrows) hout[(size_t)(n0 + q) * HDIM + j] = hv;
      float v = tanhf(hv) * waw;
#pragma unroll
      for (int off = 32; off > 0; off >>= 1) v += __shfl_down(v, off, 64);
      if (lane == 0) red[q][wid] = v;
    }
  }
  __syncthreads();
  if (j < NB) {
    int n = n0 + j;
    if (n < nrows) {
      float l = red[j][0] + red[j][1] + baw[0];
      float m = mxv[n];
      float mnew = fmaxf(m, l);
      float fac = expf(m - mnew);
      float p = expf(l - mnew);
      facs[j] = fac;
      ps[j] = p;
      sden[n] = sden[n] * fac + p;
      mxv[n] = mnew;
    }
  }
  __syncthreads();
  if (j < HDIM) {
#pragma unroll
    for (int q = 0; q < NB; ++q) {
      int n = n0 + q;
      if (n < nrows) {
        size_t off = (size_t)n * HDIM + j;
        acc[off] = acc[off] * facs[q] + ps[q] * hn[q];
      }
    }
  }
}

// ---- finalize: out /= s ------------------------------------------------------------------
__global__ __launch_bounds__(256) void attn_finalize(
    float* __restrict__ acc, const float* __restrict__ s) {
  int idx = blockIdx.x * 256 + threadIdx.x;
  if (idx >= NNODES * HDIM) return;
  acc[idx] = acc[idx] / s[idx >> 7];
}

extern "C" void kernel_launch(void* const* d_in, const int* in_sizes, int n_in,
                              void* d_out, int out_size, void* d_ws, size_t ws_size,
                              hipStream_t stream) {
  const float* static_dense = (const float*)d_in[0];
  const int*   static_sparse = (const int*)d_in[1];
  const float* dyn_dense = (const float*)d_in[2];
  const int*   dyn_sparse = (const int*)d_in[3];
  const int*   edges = (const int*)d_in[4];
  const float* weights = (const float*)d_in[5];
  const float* s_emb = (const float*)d_in[6];
  const float* d_emb = (const float*)d_in[7];
  const float* Ws = (const float*)d_in[8];
  const float* bs = (const float*)d_in[9];
  const float* gW1 = (const float*)d_in[10];
  const float* gb1 = (const float*)d_in[11];
  const float* gW2 = (const float*)d_in[12];
  const float* gb2 = (const float*)d_in[13];
  const float* Wx = (const float*)d_in[14];
  const float* Wh = (const float*)d_in[15];
  const float* bx = (const float*)d_in[16];
  const float* bh = (const float*)d_in[17];
  const float* Waw = (const float*)d_in[18];
  const float* baw = (const float*)d_in[19];
  float* out = (float*)d_out;  // attention accumulator [N,128]

  const size_t N = NNODES;
  float* ws = (float*)d_ws;
  float* sden = ws;                    // N
  float* mxv  = sden + N;              // N
  float* hA   = mxv + N;               // N*128
  float* hB   = hA + N * HDIM;         // N*128
  float* R1   = hB + N * HDIM;         // N*128: dynx(N*64)|m1(N*64), then m2(N*128)
  float* h1   = R1 + N * HDIM;         // N*128
  float* Wf   = h1 + N * HDIM;         // 8*128*384
  float* bfb  = Wf + (size_t)TSTEPS * HDIM * H3;    // 8*384
  float* csr_w = bfb + TSTEPS * H3;    // E
  int* deg    = (int*)(csr_w + NEDGES);  // N
  int* offs   = deg + N;               // N+1
  int* cursor = offs + N + 1;          // N
  int* csr_src = cursor + N;           // E
  float* dynx = R1;
  float* m1   = R1 + N * G0DIM;
  float* m2   = R1;

  fuse_w<<<TSTEPS * HDIM, H3, 0, stream>>>(gW2, Wx, Wf);
  fuse_b<<<TSTEPS, H3, 0, stream>>>(gb2, Wx, bx, bfb);

  static_encode_attn_init<<<NNODES, 128, 0, stream>>>(
      static_dense, static_sparse, s_emb, Ws, bs, Waw, baw, out, sden, mxv);

  const int EB = (NEDGES + 255) / 256;
  for (int t = 0; t < TSTEPS; ++t) {
    const int* e_src = edges + (size_t)t * 2 * NEDGES;
    const int* e_dst = e_src + NEDGES;
    const float* w_t = weights + (size_t)t * NEDGES;
    float* hcur = (t & 1) ? hB : hA;
    const float* hprev = (t == 0) ? nullptr : ((t & 1) ? hA : hB);

    // CSR build for this timestep
    fill_zero_int<<<(NNODES + 255) / 256, 256, 0, stream>>>(deg, NNODES);
    hist_dst<<<EB, 256, 0, stream>>>(e_dst, deg);
    scan_deg<<<1, 1024, 0, stream>>>(deg, offs, cursor);
    fill_csr<<<EB, 256, 0, stream>>>(e_src, e_dst, w_t, cursor, csr_src, csr_w);

    dynx_gather4<<<(NNODES * 16 + 255) / 256, 256, 0, stream>>>(
        dyn_dense + (size_t)t * N * DDIM, dyn_sparse + (size_t)t * N * 2, d_emb,
        (float4*)dynx);

    gather_agg<G0DIM><<<(NNODES + 3) / 4, 256, 0, stream>>>(offs, csr_src, csr_w, dynx, m1);

    rowmm_t<G0DIM, HDIM, true><<<(NNODES + 7) / 8, HDIM, 0, stream>>>(
        m1, gW1 + (size_t)t * G0DIM * HDIM, gb1 + (size_t)t * HDIM, h1, NNODES);

    gather_agg<HDIM><<<(NNODES + 1) / 2, 256, 0, stream>>>(offs, csr_src, csr_w, h1, m2);

    gru_fused<<<(NNODES + 7) / 8, 384, 0, stream>>>(
        m2, hprev, Wf + (size_t)t * HDIM * H3, Wh, bfb + t * H3, bh,
        Waw, baw, hcur, out, sden, mxv, NNODES);
  }

  attn_finalize<<<(NNODES * HDIM + 255) / 256, 256, 0, stream>>>(out, sden);
}

// Round 5
// 4601.427 us; speedup vs baseline: 4.1134x; 1.2175x over previous
//
#include <hip/hip_runtime.h>
#include <hip/hip_bf16.h>

#define NNODES 50000
#define TSTEPS 8
#define NEDGES 800000
#define VVOCAB 1000
#define DDIM 32
#define HDIM 128
#define G0DIM 64
#define H3 384

// ---------------- zero fill for int counters ---------------------------------------------
__global__ __launch_bounds__(256) void fill_zero_int(int* __restrict__ p, int n) {
  int i = blockIdx.x * 256 + threadIdx.x;
  if (i < n) p[i] = 0;
}

// ---------------- CSR build: histogram ----------------------------------------------------
__global__ __launch_bounds__(256) void hist_dst(const int* __restrict__ e_dst,
                                                int* __restrict__ deg) {
  int e = blockIdx.x * 256 + threadIdx.x;
  if (e < NEDGES) atomicAdd(&deg[e_dst[e]], 1);
}

// ---------------- CSR build: single-block scan (off = exclusive prefix, off[N]=E) ---------
__global__ __launch_bounds__(1024) void scan_deg(const int* __restrict__ deg,
                                                 int* __restrict__ off,
                                                 int* __restrict__ cursor) {
  const int T = 1024;
  const int CH = (NNODES + T - 1) / T;  // 49
  int t = threadIdx.x;
  int start = t * CH;
  int end = min(start + CH, NNODES);
  __shared__ int buf[T];
  int s = 0;
  for (int i = start; i < end; ++i) s += deg[i];
  buf[t] = s;
  __syncthreads();
  for (int d = 1; d < T; d <<= 1) {
    int v = (t >= d) ? buf[t - d] : 0;
    __syncthreads();
    buf[t] += v;
    __syncthreads();
  }
  int pre = (t == 0) ? 0 : buf[t - 1];
  for (int i = start; i < end; ++i) {
    off[i] = pre;
    cursor[i] = pre;
    pre += deg[i];
  }
  if (t == T - 1) off[NNODES] = buf[T - 1];
}

// ---------------- CSR build: bucket fill (packed src+w, one 8B store) ---------------------
__global__ __launch_bounds__(256) void fill_csr(
    const int* __restrict__ e_src, const int* __restrict__ e_dst,
    const float* __restrict__ w, int* __restrict__ cursor,
    int2* __restrict__ csr) {
  int e = blockIdx.x * 256 + threadIdx.x;
  if (e >= NEDGES) return;
  int d = e_dst[e];
  int pos = atomicAdd(&cursor[d], 1);
  int2 pk;
  pk.x = e_src[e];
  pk.y = __float_as_int(w[e]);
  csr[pos] = pk;
}

// ---------------- pull aggregation: m[n,:] = sum_e w_e * x[src_e,:], float4 lanes ---------
template <int D, int LPN>  // LPN = D/4 lanes per node
__global__ __launch_bounds__(256) void gather_agg(
    const int* __restrict__ off, const int2* __restrict__ csr,
    const float* __restrict__ x, float* __restrict__ m) {
  const int NPB = 256 / LPN;
  int n = blockIdx.x * NPB + threadIdx.x / LPN;
  int l = threadIdx.x % LPN;
  if (n >= NNODES) return;
  int s0 = off[n], s1 = off[n + 1];
  float a0x = 0.f, a0y = 0.f, a0z = 0.f, a0w = 0.f;
  float a1x = 0.f, a1y = 0.f, a1z = 0.f, a1w = 0.f;
  int e = s0;
  for (; e + 1 < s1; e += 2) {
    int2 eA = csr[e], eB = csr[e + 1];
    float4 xA = *(const float4*)&x[(size_t)eA.x * D + l * 4];
    float4 xB = *(const float4*)&x[(size_t)eB.x * D + l * 4];
    float wA = __int_as_float(eA.y), wB = __int_as_float(eB.y);
    a0x += wA * xA.x; a0y += wA * xA.y; a0z += wA * xA.z; a0w += wA * xA.w;
    a1x += wB * xB.x; a1y += wB * xB.y; a1z += wB * xB.z; a1w += wB * xB.w;
  }
  if (e < s1) {
    int2 eA = csr[e];
    float4 xA = *(const float4*)&x[(size_t)eA.x * D + l * 4];
    float wA = __int_as_float(eA.y);
    a0x += wA * xA.x; a0y += wA * xA.y; a0z += wA * xA.z; a0w += wA * xA.w;
  }
  float4 r;
  r.x = a0x + a1x; r.y = a0y + a1y; r.z = a0z + a1z; r.w = a0w + a1w;
  *(float4*)&m[(size_t)n * D + l * 4] = r;
}

// ---- fused weight precompute: Wf[t] = W2_t @ Wx  ([128,128]@[128,384]) -------------------
__global__ __launch_bounds__(384) void fuse_w(
    const float* __restrict__ gW2, const float* __restrict__ Wx, float* __restrict__ Wf) {
  int t = blockIdx.x >> 7;
  int k = blockIdx.x & 127;
  int j = threadIdx.x;
  __shared__ float row[HDIM];
  if (j < HDIM) row[j] = gW2[((size_t)t * HDIM + k) * HDIM + j];
  __syncthreads();
  float acc = 0.f;
#pragma unroll 8
  for (int c = 0; c < HDIM; ++c) acc += row[c] * Wx[c * H3 + j];
  Wf[((size_t)t * HDIM + k) * H3 + j] = acc;
}

// ---- fused bias precompute: bf[t] = b2_t @ Wx + bx ---------------------------------------
__global__ __launch_bounds__(384) void fuse_b(
    const float* __restrict__ gb2, const float* __restrict__ Wx,
    const float* __restrict__ bx, float* __restrict__ bf) {
  int t = blockIdx.x;
  int j = threadIdx.x;
  __shared__ float row[HDIM];
  if (j < HDIM) row[j] = gb2[t * HDIM + j];
  __syncthreads();
  float acc = bx[j];
#pragma unroll 8
  for (int c = 0; c < HDIM; ++c) acc += row[c] * Wx[c * H3 + j];
  bf[t * H3 + j] = acc;
}

// ---- static encoder + attention init: acc=se, mx=logit(se), s=1 ------------------------
__global__ __launch_bounds__(128) void static_encode_attn_init(
    const float* __restrict__ dense, const int* __restrict__ sparse,
    const float* __restrict__ emb,   // (2,V,16)
    const float* __restrict__ Ws, const float* __restrict__ bs,
    const float* __restrict__ Waw, const float* __restrict__ baw,
    float* __restrict__ acc, float* __restrict__ s, float* __restrict__ mx) {
  int n = blockIdx.x;
  int j = threadIdx.x; // 0..127
  __shared__ float xs[G0DIM];
  if (j < G0DIM) {
    float v;
    if (j < 16) {
      v = emb[sparse[n * 2 + 0] * 16 + j];
    } else if (j < 32) {
      v = emb[VVOCAB * 16 + sparse[n * 2 + 1] * 16 + (j - 16)];
    } else {
      v = dense[n * DDIM + (j - 32)];
    }
    xs[j] = v;
  }
  __syncthreads();
  float a = bs[j];
#pragma unroll 16
  for (int k = 0; k < G0DIM; ++k) a += xs[k] * Ws[k * HDIM + j];
  a = fmaxf(a, 0.f);
  float v = tanhf(a) * Waw[j];
  __shared__ float red[2];
  int lane = j & 63, wid = j >> 6;
#pragma unroll
  for (int off = 32; off > 0; off >>= 1) v += __shfl_down(v, off, 64);
  if (lane == 0) red[wid] = v;
  __syncthreads();
  acc[(size_t)n * HDIM + j] = a;  // weight exp(l-m)=1 since m=l
  if (j == 0) {
    s[n] = 1.f;
    mx[n] = red[0] + red[1] + baw[0];
  }
}

// ---------------- dynamic feature gather, float4 per thread ------------------------------
__global__ __launch_bounds__(256) void dynx_gather4(
    const float* __restrict__ dense_t, const int* __restrict__ sparse_t,
    const float* __restrict__ emb, float4* __restrict__ xout) {
  int idx = blockIdx.x * 256 + threadIdx.x;  // over N*16
  int n = idx >> 4, k4 = idx & 15;
  if (n >= NNODES) return;
  float4 v;
  if (k4 < 4)
    v = *(const float4*)&emb[sparse_t[n * 2 + 0] * 16 + k4 * 4];
  else if (k4 < 8)
    v = *(const float4*)&emb[VVOCAB * 16 + sparse_t[n * 2 + 1] * 16 + (k4 - 4) * 4];
  else
    v = *(const float4*)&dense_t[n * DDIM + (k4 - 8) * 4];
  xout[idx] = v;
}

// ---------------- row matmul: 64 thr, NB=8 nodes, C=2 cols/thread ------------------------
// y[n,:] = relu(x[n,:] @ W + b), x: [N,64], W: [64,128]
__global__ __launch_bounds__(64) void rowmm64(
    const float* __restrict__ x, const float* __restrict__ W,
    const float* __restrict__ b, float* __restrict__ y) {
  const int NB = 8;
  int n0 = blockIdx.x * NB;
  int j = threadIdx.x;  // 0..63
  __shared__ float xT[G0DIM][12];  // [k][q], stride 12 floats keeps float4 aligned
#pragma unroll
  for (int q = 0; q < NB; ++q) xT[j][q] = x[(size_t)(n0 + q) * G0DIM + j];
  __syncthreads();
  float acc0[NB], acc1[NB];
#pragma unroll
  for (int q = 0; q < NB; ++q) { acc0[q] = 0.f; acc1[q] = 0.f; }
#pragma unroll 4
  for (int k = 0; k < G0DIM; ++k) {
    float4 a = *(const float4*)&xT[k][0];
    float4 c = *(const float4*)&xT[k][4];
    float w0 = W[(size_t)k * HDIM + j];
    float w1 = W[(size_t)k * HDIM + j + 64];
    acc0[0] += a.x * w0; acc0[1] += a.y * w0; acc0[2] += a.z * w0; acc0[3] += a.w * w0;
    acc0[4] += c.x * w0; acc0[5] += c.y * w0; acc0[6] += c.z * w0; acc0[7] += c.w * w0;
    acc1[0] += a.x * w1; acc1[1] += a.y * w1; acc1[2] += a.z * w1; acc1[3] += a.w * w1;
    acc1[4] += c.x * w1; acc1[5] += c.y * w1; acc1[6] += c.z * w1; acc1[7] += c.w * w1;
  }
  float b0 = b[j], b1 = b[j + 64];
#pragma unroll
  for (int q = 0; q < NB; ++q) {
    y[(size_t)(n0 + q) * HDIM + j] = fmaxf(acc0[q] + b0, 0.f);
    y[(size_t)(n0 + q) * HDIM + j + 64] = fmaxf(acc1[q] + b1, 0.f);
  }
}

__device__ __forceinline__ float sigmoidf_(float v) {
  return 1.f / (1.f + expf(-v));
}

// ---------------- fused GRU step + attention: 64 thr, NB=8 nodes, C=6 cols ---------------
// gx = m2 @ Wf + bf; gh = hprev @ Wh + bh; GRU; online-softmax attn update.
// thread j owns 384-cols {j+64c: c=0..5} -> gates (r,z,n) for output cols j and j+64.
__global__ __launch_bounds__(64) void gru_fused(
    const float* __restrict__ m2, const float* __restrict__ hprev,
    const float* __restrict__ Wf, const float* __restrict__ Wh,
    const float* __restrict__ bf, const float* __restrict__ bh,
    const float* __restrict__ Waw, const float* __restrict__ baw,
    float* __restrict__ hout, float* __restrict__ acc,
    float* __restrict__ sden, float* __restrict__ mxv) {
  const int NB = 8;
  int n0 = blockIdx.x * NB;
  int j = threadIdx.x;  // 0..63
  __shared__ float xT[HDIM][12];  // m2 transposed  [k][q]
  __shared__ float hT[HDIM][12];  // hprev transposed
  __shared__ float lg[NB];        // attn partial logits
  __shared__ float facs[NB], ps[NB];

#pragma unroll
  for (int q = 0; q < NB; ++q) {
    size_t base = (size_t)(n0 + q) * HDIM;
    xT[j][q] = m2[base + j];
    xT[j + 64][q] = m2[base + j + 64];
    float h0 = hprev ? hprev[base + j] : 0.f;
    float h1 = hprev ? hprev[base + j + 64] : 0.f;
    hT[j][q] = h0;
    hT[j + 64][q] = h1;
  }
  __syncthreads();

  float ax[6][NB], ah[6][NB];
#pragma unroll
  for (int c = 0; c < 6; ++c)
#pragma unroll
    for (int q = 0; q < NB; ++q) { ax[c][q] = 0.f; ah[c][q] = 0.f; }

#pragma unroll 2
  for (int k = 0; k < HDIM; ++k) {
    float4 a0 = *(const float4*)&xT[k][0];
    float4 a1 = *(const float4*)&xT[k][4];
    float4 h0 = *(const float4*)&hT[k][0];
    float4 h1 = *(const float4*)&hT[k][4];
    size_t wbase = (size_t)k * H3 + j;
#pragma unroll
    for (int c = 0; c < 6; ++c) {
      float wf = Wf[wbase + 64 * c];
      float wh = Wh[wbase + 64 * c];
      ax[c][0] += a0.x * wf; ax[c][1] += a0.y * wf; ax[c][2] += a0.z * wf; ax[c][3] += a0.w * wf;
      ax[c][4] += a1.x * wf; ax[c][5] += a1.y * wf; ax[c][6] += a1.z * wf; ax[c][7] += a1.w * wf;
      ah[c][0] += h0.x * wh; ah[c][1] += h0.y * wh; ah[c][2] += h0.z * wh; ah[c][3] += h0.w * wh;
      ah[c][4] += h1.x * wh; ah[c][5] += h1.y * wh; ah[c][6] += h1.z * wh; ah[c][7] += h1.w * wh;
    }
  }

  float bfv[6], bhv[6];
#pragma unroll
  for (int c = 0; c < 6; ++c) {
    bfv[c] = bf[j + 64 * c];
    bhv[c] = bh[j + 64 * c];
  }
  float waw0 = Waw[j], waw1 = Waw[j + 64];

  float hn0[NB], hn1[NB];
#pragma unroll
  for (int q = 0; q < NB; ++q) {
    // output col j  (gates at c = 0,2,4)
    float r0 = sigmoidf_(ax[0][q] + bfv[0] + ah[0][q] + bhv[0]);
    float z0 = sigmoidf_(ax[2][q] + bfv[2] + ah[2][q] + bhv[2]);
    float n0c = tanhf(ax[4][q] + bfv[4] + r0 * (ah[4][q] + bhv[4]));
    float hp0 = hT[j][q];
    hn0[q] = (1.f - z0) * n0c + z0 * hp0;
    // output col j+64 (gates at c = 1,3,5)
    float r1 = sigmoidf_(ax[1][q] + bfv[1] + ah[1][q] + bhv[1]);
    float z1 = sigmoidf_(ax[3][q] + bfv[3] + ah[3][q] + bhv[3]);
    float n1c = tanhf(ax[5][q] + bfv[5] + r1 * (ah[5][q] + bhv[5]));
    float hp1 = hT[j + 64][q];
    hn1[q] = (1.f - z1) * n1c + z1 * hp1;
  }

  // attention logits: per node q, reduce tanh(h)*Waw over 128 cols (one wave)
#pragma unroll
  for (int q = 0; q < NB; ++q) {
    float v = tanhf(hn0[q]) * waw0 + tanhf(hn1[q]) * waw1;
#pragma unroll
    for (int off = 32; off > 0; off >>= 1) v += __shfl_down(v, off, 64);
    if (j == 0) lg[q] = v;
  }
  __syncthreads();
  if (j < NB) {
    int n = n0 + j;
    float l = lg[j] + baw[0];
    float m = mxv[n];
    float mnew = fmaxf(m, l);
    float fac = expf(m - mnew);
    float p = expf(l - mnew);
    facs[j] = fac;
    ps[j] = p;
    sden[n] = sden[n] * fac + p;
    mxv[n] = mnew;
  }
  __syncthreads();
#pragma unroll
  for (int q = 0; q < NB; ++q) {
    size_t base = (size_t)(n0 + q) * HDIM;
    hout[base + j] = hn0[q];
    hout[base + j + 64] = hn1[q];
    acc[base + j] = acc[base + j] * facs[q] + ps[q] * hn0[q];
    acc[base + j + 64] = acc[base + j + 64] * facs[q] + ps[q] * hn1[q];
  }
}

// ---- finalize: out /= s ------------------------------------------------------------------
__global__ __launch_bounds__(256) void attn_finalize(
    float* __restrict__ acc, const float* __restrict__ s) {
  int idx = blockIdx.x * 256 + threadIdx.x;
  if (idx >= NNODES * HDIM) return;
  acc[idx] = acc[idx] / s[idx >> 7];
}

extern "C" void kernel_launch(void* const* d_in, const int* in_sizes, int n_in,
                              void* d_out, int out_size, void* d_ws, size_t ws_size,
                              hipStream_t stream) {
  const float* static_dense = (const float*)d_in[0];
  const int*   static_sparse = (const int*)d_in[1];
  const float* dyn_dense = (const float*)d_in[2];
  const int*   dyn_sparse = (const int*)d_in[3];
  const int*   edges = (const int*)d_in[4];
  const float* weights = (const float*)d_in[5];
  const float* s_emb = (const float*)d_in[6];
  const float* d_emb = (const float*)d_in[7];
  const float* Ws = (const float*)d_in[8];
  const float* bs = (const float*)d_in[9];
  const float* gW1 = (const float*)d_in[10];
  const float* gb1 = (const float*)d_in[11];
  const float* gW2 = (const float*)d_in[12];
  const float* gb2 = (const float*)d_in[13];
  const float* Wx = (const float*)d_in[14];
  const float* Wh = (const float*)d_in[15];
  const float* bx = (const float*)d_in[16];
  const float* bh = (const float*)d_in[17];
  const float* Waw = (const float*)d_in[18];
  const float* baw = (const float*)d_in[19];
  float* out = (float*)d_out;  // attention accumulator [N,128]

  const size_t N = NNODES;
  float* ws = (float*)d_ws;
  float* sden = ws;                    // N
  float* mxv  = sden + N;              // N
  float* hA   = mxv + N;               // N*128
  float* hB   = hA + N * HDIM;         // N*128
  float* R1   = hB + N * HDIM;         // N*128: dynx(N*64)|m1(N*64), then m2(N*128)
  float* h1   = R1 + N * HDIM;         // N*128
  float* Wf   = h1 + N * HDIM;         // 8*128*384
  float* bfb  = Wf + (size_t)TSTEPS * HDIM * H3;    // 8*384
  int* deg    = (int*)(bfb + TSTEPS * H3);  // N
  int* offs   = deg + N;               // N+1
  int* cursor = offs + N + 1;          // N
  int2* csr   = (int2*)(cursor + N);   // E int2 (8B-aligned: offset from ws is even)
  float* dynx = R1;
  float* m1   = R1 + N * G0DIM;
  float* m2   = R1;

  fuse_w<<<TSTEPS * HDIM, H3, 0, stream>>>(gW2, Wx, Wf);
  fuse_b<<<TSTEPS, H3, 0, stream>>>(gb2, Wx, bx, bfb);

  static_encode_attn_init<<<NNODES, 128, 0, stream>>>(
      static_dense, static_sparse, s_emb, Ws, bs, Waw, baw, out, sden, mxv);

  const int EB = (NEDGES + 255) / 256;
  for (int t = 0; t < TSTEPS; ++t) {
    const int* e_src = edges + (size_t)t * 2 * NEDGES;
    const int* e_dst = e_src + NEDGES;
    const float* w_t = weights + (size_t)t * NEDGES;
    float* hcur = (t & 1) ? hB : hA;
    const float* hprev = (t == 0) ? nullptr : ((t & 1) ? hA : hB);

    // CSR build for this timestep
    fill_zero_int<<<(NNODES + 255) / 256, 256, 0, stream>>>(deg, NNODES);
    hist_dst<<<EB, 256, 0, stream>>>(e_dst, deg);
    scan_deg<<<1, 1024, 0, stream>>>(deg, offs, cursor);
    fill_csr<<<EB, 256, 0, stream>>>(e_src, e_dst, w_t, cursor, csr);

    dynx_gather4<<<(NNODES * 16 + 255) / 256, 256, 0, stream>>>(
        dyn_dense + (size_t)t * N * DDIM, dyn_sparse + (size_t)t * N * 2, d_emb,
        (float4*)dynx);

    gather_agg<G0DIM, 16><<<(NNODES + 15) / 16, 256, 0, stream>>>(offs, csr, dynx, m1);

    rowmm64<<<NNODES / 8, 64, 0, stream>>>(
        m1, gW1 + (size_t)t * G0DIM * HDIM, gb1 + (size_t)t * HDIM, h1);

    gather_agg<HDIM, 32><<<(NNODES + 7) / 8, 256, 0, stream>>>(offs, csr, h1, m2);

    gru_fused<<<NNODES / 8, 64, 0, stream>>>(
        m2, hprev, Wf + (size_t)t * HDIM * H3, Wh, bfb + t * H3, bh,
        Waw, baw, hcur, out, sden, mxv);
  }

  attn_finalize<<<(NNODES * HDIM + 255) / 256, 256, 0, stream>>>(out, sden);
}

// Round 6
// 4519.658 us; speedup vs baseline: 4.1878x; 1.0181x over previous
//
#include <hip/hip_runtime.h>
#include <hip/hip_bf16.h>

#define NNODES 50000
#define TSTEPS 8
#define NEDGES 800000
#define VVOCAB 1000
#define DDIM 32
#define HDIM 128
#define G0DIM 64
#define H3 384

// ---------------- zero fill for int counters ---------------------------------------------
__global__ __launch_bounds__(256) void fill_zero_int(int* __restrict__ p, int n) {
  int i = blockIdx.x * 256 + threadIdx.x;
  if (i < n) p[i] = 0;
}

// ---------------- CSR build: histogram ----------------------------------------------------
__global__ __launch_bounds__(256) void hist_dst(const int* __restrict__ e_dst,
                                                int* __restrict__ deg) {
  int e = blockIdx.x * 256 + threadIdx.x;
  if (e < NEDGES) atomicAdd(&deg[e_dst[e]], 1);
}

// ---------------- CSR build: single-block scan (off = exclusive prefix, off[N]=E) ---------
__global__ __launch_bounds__(1024) void scan_deg(const int* __restrict__ deg,
                                                 int* __restrict__ off,
                                                 int* __restrict__ cursor) {
  const int T = 1024;
  const int CH = (NNODES + T - 1) / T;  // 49
  int t = threadIdx.x;
  int start = t * CH;
  int end = min(start + CH, NNODES);
  __shared__ int buf[T];
  int s = 0;
  for (int i = start; i < end; ++i) s += deg[i];
  buf[t] = s;
  __syncthreads();
  for (int d = 1; d < T; d <<= 1) {
    int v = (t >= d) ? buf[t - d] : 0;
    __syncthreads();
    buf[t] += v;
    __syncthreads();
  }
  int pre = (t == 0) ? 0 : buf[t - 1];
  for (int i = start; i < end; ++i) {
    off[i] = pre;
    cursor[i] = pre;
    pre += deg[i];
  }
  if (t == T - 1) off[NNODES] = buf[T - 1];
}

// ---------------- CSR build: bucket fill (packed src+w, one 8B store) ---------------------
__global__ __launch_bounds__(256) void fill_csr(
    const int* __restrict__ e_src, const int* __restrict__ e_dst,
    const float* __restrict__ w, int* __restrict__ cursor,
    int2* __restrict__ csr) {
  int e = blockIdx.x * 256 + threadIdx.x;
  if (e >= NEDGES) return;
  int d = e_dst[e];
  int pos = atomicAdd(&cursor[d], 1);
  int2 pk;
  pk.x = e_src[e];
  pk.y = __float_as_int(w[e]);
  csr[pos] = pk;
}

// ---------------- pull aggregation, 4-edge unrolled ---------------------------------------
template <int D, int LPN>  // LPN = D/4 lanes per node
__global__ __launch_bounds__(256) void gather_agg(
    const int* __restrict__ off, const int2* __restrict__ csr,
    const float* __restrict__ x, float* __restrict__ m) {
  const int NPB = 256 / LPN;
  int n = blockIdx.x * NPB + threadIdx.x / LPN;
  int l = threadIdx.x % LPN;
  if (n >= NNODES) return;
  int s0 = off[n], s1 = off[n + 1];
  float a0x = 0.f, a0y = 0.f, a0z = 0.f, a0w = 0.f;
  float a1x = 0.f, a1y = 0.f, a1z = 0.f, a1w = 0.f;
  int e = s0;
  for (; e + 3 < s1; e += 4) {
    int2 e0 = csr[e], e1 = csr[e + 1], e2 = csr[e + 2], e3 = csr[e + 3];
    float4 x0 = *(const float4*)&x[(size_t)e0.x * D + l * 4];
    float4 x1 = *(const float4*)&x[(size_t)e1.x * D + l * 4];
    float4 x2 = *(const float4*)&x[(size_t)e2.x * D + l * 4];
    float4 x3 = *(const float4*)&x[(size_t)e3.x * D + l * 4];
    float w0 = __int_as_float(e0.y), w1 = __int_as_float(e1.y);
    float w2 = __int_as_float(e2.y), w3 = __int_as_float(e3.y);
    a0x += w0 * x0.x + w2 * x2.x; a0y += w0 * x0.y + w2 * x2.y;
    a0z += w0 * x0.z + w2 * x2.z; a0w += w0 * x0.w + w2 * x2.w;
    a1x += w1 * x1.x + w3 * x3.x; a1y += w1 * x1.y + w3 * x3.y;
    a1z += w1 * x1.z + w3 * x3.z; a1w += w1 * x1.w + w3 * x3.w;
  }
  for (; e < s1; ++e) {
    int2 eA = csr[e];
    float4 xA = *(const float4*)&x[(size_t)eA.x * D + l * 4];
    float wA = __int_as_float(eA.y);
    a0x += wA * xA.x; a0y += wA * xA.y; a0z += wA * xA.z; a0w += wA * xA.w;
  }
  float4 r;
  r.x = a0x + a1x; r.y = a0y + a1y; r.z = a0z + a1z; r.w = a0w + a1w;
  *(float4*)&m[(size_t)n * D + l * 4] = r;
}

// ---- fused weight precompute: Wf[t] = W2_t @ Wx, written in thread-packed layout ---------
// col = j + 64c (j=0..63, c=0..5): WfA[(t*128+k)*64+j][c] for c<4, WfB[...][c-4] for c>=4
__global__ __launch_bounds__(384) void fuse_w(
    const float* __restrict__ gW2, const float* __restrict__ Wx,
    float* __restrict__ WfA, float* __restrict__ WfB) {
  int t = blockIdx.x >> 7;
  int k = blockIdx.x & 127;
  int j2 = threadIdx.x;  // col 0..383
  __shared__ float row[HDIM];
  if (j2 < HDIM) row[j2] = gW2[((size_t)t * HDIM + k) * HDIM + j2];
  __syncthreads();
  float acc = 0.f;
#pragma unroll 8
  for (int c = 0; c < HDIM; ++c) acc += row[c] * Wx[c * H3 + j2];
  int j = j2 & 63, c = j2 >> 6;
  size_t slot = ((size_t)t * HDIM + k) * 64 + j;
  if (c < 4) WfA[slot * 4 + c] = acc;
  else WfB[slot * 2 + (c - 4)] = acc;
}

// ---- rearrange Wh into the same thread-packed layout -------------------------------------
__global__ __launch_bounds__(384) void rearrange_wh(
    const float* __restrict__ Wh, float* __restrict__ WhA, float* __restrict__ WhB) {
  int k = blockIdx.x;  // 0..127
  int j2 = threadIdx.x;
  float v = Wh[(size_t)k * H3 + j2];
  int j = j2 & 63, c = j2 >> 6;
  size_t slot = (size_t)k * 64 + j;
  if (c < 4) WhA[slot * 4 + c] = v;
  else WhB[slot * 2 + (c - 4)] = v;
}

// ---- fused bias precompute: bf[t] = b2_t @ Wx + bx ---------------------------------------
__global__ __launch_bounds__(384) void fuse_b(
    const float* __restrict__ gb2, const float* __restrict__ Wx,
    const float* __restrict__ bx, float* __restrict__ bf) {
  int t = blockIdx.x;
  int j = threadIdx.x;
  __shared__ float row[HDIM];
  if (j < HDIM) row[j] = gb2[t * HDIM + j];
  __syncthreads();
  float acc = bx[j];
#pragma unroll 8
  for (int c = 0; c < HDIM; ++c) acc += row[c] * Wx[c * H3 + j];
  bf[t * H3 + j] = acc;
}

// ---- static encoder + attention init: acc=se, mx=logit(se), s=1 ------------------------
__global__ __launch_bounds__(128) void static_encode_attn_init(
    const float* __restrict__ dense, const int* __restrict__ sparse,
    const float* __restrict__ emb,   // (2,V,16)
    const float* __restrict__ Ws, const float* __restrict__ bs,
    const float* __restrict__ Waw, const float* __restrict__ baw,
    float* __restrict__ acc, float* __restrict__ s, float* __restrict__ mx) {
  int n = blockIdx.x;
  int j = threadIdx.x; // 0..127
  __shared__ float xs[G0DIM];
  if (j < G0DIM) {
    float v;
    if (j < 16) {
      v = emb[sparse[n * 2 + 0] * 16 + j];
    } else if (j < 32) {
      v = emb[VVOCAB * 16 + sparse[n * 2 + 1] * 16 + (j - 16)];
    } else {
      v = dense[n * DDIM + (j - 32)];
    }
    xs[j] = v;
  }
  __syncthreads();
  float a = bs[j];
#pragma unroll 16
  for (int k = 0; k < G0DIM; ++k) a += xs[k] * Ws[k * HDIM + j];
  a = fmaxf(a, 0.f);
  float v = tanhf(a) * Waw[j];
  __shared__ float red[2];
  int lane = j & 63, wid = j >> 6;
#pragma unroll
  for (int off = 32; off > 0; off >>= 1) v += __shfl_down(v, off, 64);
  if (lane == 0) red[wid] = v;
  __syncthreads();
  acc[(size_t)n * HDIM + j] = a;  // weight exp(l-m)=1 since m=l
  if (j == 0) {
    s[n] = 1.f;
    mx[n] = red[0] + red[1] + baw[0];
  }
}

// ---------------- dynamic feature gather, float4 per thread ------------------------------
__global__ __launch_bounds__(256) void dynx_gather4(
    const float* __restrict__ dense_t, const int* __restrict__ sparse_t,
    const float* __restrict__ emb, float4* __restrict__ xout) {
  int idx = blockIdx.x * 256 + threadIdx.x;  // over N*16
  int n = idx >> 4, k4 = idx & 15;
  if (n >= NNODES) return;
  float4 v;
  if (k4 < 4)
    v = *(const float4*)&emb[sparse_t[n * 2 + 0] * 16 + k4 * 4];
  else if (k4 < 8)
    v = *(const float4*)&emb[VVOCAB * 16 + sparse_t[n * 2 + 1] * 16 + (k4 - 4) * 4];
  else
    v = *(const float4*)&dense_t[n * DDIM + (k4 - 8) * 4];
  xout[idx] = v;
}

// ---------------- row matmul: 64 thr, NB=8 nodes, C=2 cols/thread ------------------------
__global__ __launch_bounds__(64) void rowmm64(
    const float* __restrict__ x, const float* __restrict__ W,
    const float* __restrict__ b, float* __restrict__ y) {
  const int NB = 8;
  int n0 = blockIdx.x * NB;
  int j = threadIdx.x;  // 0..63
  __shared__ float xT[G0DIM][12];
#pragma unroll
  for (int q = 0; q < NB; ++q) xT[j][q] = x[(size_t)(n0 + q) * G0DIM + j];
  __syncthreads();
  float acc0[NB], acc1[NB];
#pragma unroll
  for (int q = 0; q < NB; ++q) { acc0[q] = 0.f; acc1[q] = 0.f; }
#pragma unroll 4
  for (int k = 0; k < G0DIM; ++k) {
    float4 a = *(const float4*)&xT[k][0];
    float4 c = *(const float4*)&xT[k][4];
    float w0 = W[(size_t)k * HDIM + j];
    float w1 = W[(size_t)k * HDIM + j + 64];
    acc0[0] += a.x * w0; acc0[1] += a.y * w0; acc0[2] += a.z * w0; acc0[3] += a.w * w0;
    acc0[4] += c.x * w0; acc0[5] += c.y * w0; acc0[6] += c.z * w0; acc0[7] += c.w * w0;
    acc1[0] += a.x * w1; acc1[1] += a.y * w1; acc1[2] += a.z * w1; acc1[3] += a.w * w1;
    acc1[4] += c.x * w1; acc1[5] += c.y * w1; acc1[6] += c.z * w1; acc1[7] += c.w * w1;
  }
  float b0 = b[j], b1 = b[j + 64];
#pragma unroll
  for (int q = 0; q < NB; ++q) {
    y[(size_t)(n0 + q) * HDIM + j] = fmaxf(acc0[q] + b0, 0.f);
    y[(size_t)(n0 + q) * HDIM + j + 64] = fmaxf(acc1[q] + b1, 0.f);
  }
}

__device__ __forceinline__ float sigmoidf_(float v) {
  return 1.f / (1.f + expf(-v));
}

// ---------------- fused GRU + attention: 4 waves x NB=12 nodes, C=6 cols/thread ----------
// Weights in thread-packed layout: per k, thread j loads WfA(float4)+WfB(float2) and
// WhA+WhB -> 4 vector loads instead of 12 scalars. All 4 waves read the SAME weight
// addresses -> L1 reuse. r/z gates accumulate (gx+gh) merged; n gate keeps x/h split.
__global__ __launch_bounds__(256) void gru_fused(
    const float* __restrict__ m2, const float* __restrict__ hprev,
    const float4* __restrict__ WfA, const float2* __restrict__ WfB,
    const float4* __restrict__ WhA, const float2* __restrict__ WhB,
    const float* __restrict__ bf, const float* __restrict__ bh,
    const float* __restrict__ Waw, const float* __restrict__ baw,
    float* __restrict__ hout, float* __restrict__ acc,
    float* __restrict__ sden, float* __restrict__ mxv, int nrows) {
  const int NB = 12;
  int w = threadIdx.x >> 6;
  int j = threadIdx.x & 63;
  int n0 = blockIdx.x * (4 * NB) + w * NB;  // this wave's first node
  __shared__ float xT[4][HDIM][NB];
  __shared__ float hT[4][HDIM][NB];
  __shared__ float lg[4][NB];
  __shared__ float facs[4][NB], ps[4][NB];

#pragma unroll
  for (int q = 0; q < NB; ++q) {
    int n = n0 + q;
    bool ok = n < nrows;
    size_t base = (size_t)n * HDIM;
    xT[w][j][q] = ok ? m2[base + j] : 0.f;
    xT[w][j + 64][q] = ok ? m2[base + j + 64] : 0.f;
    hT[w][j][q] = (ok && hprev) ? hprev[base + j] : 0.f;
    hT[w][j + 64][q] = (ok && hprev) ? hprev[base + j + 64] : 0.f;
  }
  __syncthreads();

  // accumulators: srz[c][q] = gx+gh for gates r,z (c=0..3); axn/ahn split for n gate
  float srz[4][NB], axn[2][NB], ahn[2][NB];
#pragma unroll
  for (int q = 0; q < NB; ++q) {
    srz[0][q] = 0.f; srz[1][q] = 0.f; srz[2][q] = 0.f; srz[3][q] = 0.f;
    axn[0][q] = 0.f; axn[1][q] = 0.f; ahn[0][q] = 0.f; ahn[1][q] = 0.f;
  }

  for (int k = 0; k < HDIM; ++k) {
    const float* xk = &xT[w][k][0];
    const float* hk = &hT[w][k][0];
    float4 a0 = *(const float4*)(xk);
    float4 a1 = *(const float4*)(xk + 4);
    float4 a2 = *(const float4*)(xk + 8);
    float4 b0 = *(const float4*)(hk);
    float4 b1 = *(const float4*)(hk + 4);
    float4 b2 = *(const float4*)(hk + 8);
    size_t slot = (size_t)k * 64 + j;
    float4 wf4 = WfA[slot];
    float2 wf2 = WfB[slot];
    float4 wh4 = WhA[slot];
    float2 wh2 = WhB[slot];
    float xv[NB] = {a0.x, a0.y, a0.z, a0.w, a1.x, a1.y, a1.z, a1.w, a2.x, a2.y, a2.z, a2.w};
    float hv[NB] = {b0.x, b0.y, b0.z, b0.w, b1.x, b1.y, b1.z, b1.w, b2.x, b2.y, b2.z, b2.w};
#pragma unroll
    for (int q = 0; q < NB; ++q) {
      srz[0][q] += xv[q] * wf4.x + hv[q] * wh4.x;
      srz[1][q] += xv[q] * wf4.y + hv[q] * wh4.y;
      srz[2][q] += xv[q] * wf4.z + hv[q] * wh4.z;
      srz[3][q] += xv[q] * wf4.w + hv[q] * wh4.w;
      axn[0][q] += xv[q] * wf2.x;
      axn[1][q] += xv[q] * wf2.y;
      ahn[0][q] += hv[q] * wh2.x;
      ahn[1][q] += hv[q] * wh2.y;
    }
  }

  // biases: gate cols j+64c; c=0,1 -> r (out j, j+64); c=2,3 -> z; c=4,5 -> n
  float brz[4], bn_x[2], bn_h[2];
#pragma unroll
  for (int c = 0; c < 4; ++c) brz[c] = bf[j + 64 * c] + bh[j + 64 * c];
  bn_x[0] = bf[j + 256]; bn_x[1] = bf[j + 320];
  bn_h[0] = bh[j + 256]; bn_h[1] = bh[j + 320];
  float waw0 = Waw[j], waw1 = Waw[j + 64];

  float hn0[NB], hn1[NB];
#pragma unroll
  for (int q = 0; q < NB; ++q) {
    float r0 = sigmoidf_(srz[0][q] + brz[0]);
    float r1 = sigmoidf_(srz[1][q] + brz[1]);
    float z0 = sigmoidf_(srz[2][q] + brz[2]);
    float z1 = sigmoidf_(srz[3][q] + brz[3]);
    float nc0 = tanhf(axn[0][q] + bn_x[0] + r0 * (ahn[0][q] + bn_h[0]));
    float nc1 = tanhf(axn[1][q] + bn_x[1] + r1 * (ahn[1][q] + bn_h[1]));
    float hp0 = hT[w][j][q];
    float hp1 = hT[w][j + 64][q];
    hn0[q] = (1.f - z0) * nc0 + z0 * hp0;
    hn1[q] = (1.f - z1) * nc1 + z1 * hp1;
  }

  // attention logits: per node, reduce tanh(h)*Waw across the wave's 128 cols
#pragma unroll
  for (int q = 0; q < NB; ++q) {
    float v = tanhf(hn0[q]) * waw0 + tanhf(hn1[q]) * waw1;
#pragma unroll
    for (int off = 32; off > 0; off >>= 1) v += __shfl_down(v, off, 64);
    if (j == 0) lg[w][q] = v;
  }
  __syncthreads();
  if (j < NB) {
    int n = n0 + j;
    if (n < nrows) {
      float l = lg[w][j] + baw[0];
      float m = mxv[n];
      float mnew = fmaxf(m, l);
      float fac = expf(m - mnew);
      float p = expf(l - mnew);
      facs[w][j] = fac;
      ps[w][j] = p;
      sden[n] = sden[n] * fac + p;
      mxv[n] = mnew;
    }
  }
  __syncthreads();
#pragma unroll
  for (int q = 0; q < NB; ++q) {
    int n = n0 + q;
    if (n < nrows) {
      size_t base = (size_t)n * HDIM;
      hout[base + j] = hn0[q];
      hout[base + j + 64] = hn1[q];
      acc[base + j] = acc[base + j] * facs[w][q] + ps[w][q] * hn0[q];
      acc[base + j + 64] = acc[base + j + 64] * facs[w][q] + ps[w][q] * hn1[q];
    }
  }
}

// ---- finalize: out /= s ------------------------------------------------------------------
__global__ __launch_bounds__(256) void attn_finalize(
    float* __restrict__ acc, const float* __restrict__ s) {
  int idx = blockIdx.x * 256 + threadIdx.x;
  if (idx >= NNODES * HDIM) return;
  acc[idx] = acc[idx] / s[idx >> 7];
}

extern "C" void kernel_launch(void* const* d_in, const int* in_sizes, int n_in,
                              void* d_out, int out_size, void* d_ws, size_t ws_size,
                              hipStream_t stream) {
  const float* static_dense = (const float*)d_in[0];
  const int*   static_sparse = (const int*)d_in[1];
  const float* dyn_dense = (const float*)d_in[2];
  const int*   dyn_sparse = (const int*)d_in[3];
  const int*   edges = (const int*)d_in[4];
  const float* weights = (const float*)d_in[5];
  const float* s_emb = (const float*)d_in[6];
  const float* d_emb = (const float*)d_in[7];
  const float* Ws = (const float*)d_in[8];
  const float* bs = (const float*)d_in[9];
  const float* gW1 = (const float*)d_in[10];
  const float* gb1 = (const float*)d_in[11];
  const float* gW2 = (const float*)d_in[12];
  const float* gb2 = (const float*)d_in[13];
  const float* Wx = (const float*)d_in[14];
  const float* Wh = (const float*)d_in[15];
  const float* bx = (const float*)d_in[16];
  const float* bh = (const float*)d_in[17];
  const float* Waw = (const float*)d_in[18];
  const float* baw = (const float*)d_in[19];
  float* out = (float*)d_out;  // attention accumulator [N,128]

  const size_t N = NNODES;
  char* p = (char*)d_ws;
  auto alloc = [&](size_t bytes) { char* r = p; p += (bytes + 255) & ~(size_t)255; return r; };
  float* sden = (float*)alloc(N * 4);
  float* mxv  = (float*)alloc(N * 4);
  float* hA   = (float*)alloc(N * HDIM * 4);
  float* hB   = (float*)alloc(N * HDIM * 4);
  float* R1   = (float*)alloc(N * HDIM * 4);   // dynx(N*64)|m1(N*64), then m2(N*128)
  float* h1   = (float*)alloc(N * HDIM * 4);
  float* WfA  = (float*)alloc((size_t)TSTEPS * HDIM * 64 * 4 * 4);
  float* WfB  = (float*)alloc((size_t)TSTEPS * HDIM * 64 * 2 * 4);
  float* WhA  = (float*)alloc((size_t)HDIM * 64 * 4 * 4);
  float* WhB  = (float*)alloc((size_t)HDIM * 64 * 2 * 4);
  float* bfb  = (float*)alloc((size_t)TSTEPS * H3 * 4);
  int* deg    = (int*)alloc(N * 4);
  int* offs   = (int*)alloc((N + 1) * 4);
  int* cursor = (int*)alloc(N * 4);
  int2* csr   = (int2*)alloc((size_t)NEDGES * 8);
  float* dynx = R1;
  float* m1   = R1 + N * G0DIM;
  float* m2   = R1;

  fuse_w<<<TSTEPS * HDIM, H3, 0, stream>>>(gW2, Wx, WfA, WfB);
  rearrange_wh<<<HDIM, H3, 0, stream>>>(Wh, WhA, WhB);
  fuse_b<<<TSTEPS, H3, 0, stream>>>(gb2, Wx, bx, bfb);

  static_encode_attn_init<<<NNODES, 128, 0, stream>>>(
      static_dense, static_sparse, s_emb, Ws, bs, Waw, baw, out, sden, mxv);

  const int EB = (NEDGES + 255) / 256;
  const int GRU_BLOCKS = (NNODES + 47) / 48;
  for (int t = 0; t < TSTEPS; ++t) {
    const int* e_src = edges + (size_t)t * 2 * NEDGES;
    const int* e_dst = e_src + NEDGES;
    const float* w_t = weights + (size_t)t * NEDGES;
    float* hcur = (t & 1) ? hB : hA;
    const float* hprev = (t == 0) ? nullptr : ((t & 1) ? hA : hB);

    // CSR build for this timestep
    fill_zero_int<<<(NNODES + 255) / 256, 256, 0, stream>>>(deg, NNODES);
    hist_dst<<<EB, 256, 0, stream>>>(e_dst, deg);
    scan_deg<<<1, 1024, 0, stream>>>(deg, offs, cursor);
    fill_csr<<<EB, 256, 0, stream>>>(e_src, e_dst, w_t, cursor, csr);

    dynx_gather4<<<(NNODES * 16 + 255) / 256, 256, 0, stream>>>(
        dyn_dense + (size_t)t * N * DDIM, dyn_sparse + (size_t)t * N * 2, d_emb,
        (float4*)dynx);

    gather_agg<G0DIM, 16><<<(NNODES + 15) / 16, 256, 0, stream>>>(offs, csr, dynx, m1);

    rowmm64<<<NNODES / 8, 64, 0, stream>>>(
        m1, gW1 + (size_t)t * G0DIM * HDIM, gb1 + (size_t)t * HDIM, h1);

    gather_agg<HDIM, 32><<<(NNODES + 7) / 8, 256, 0, stream>>>(offs, csr, h1, m2);

    gru_fused<<<GRU_BLOCKS, 256, 0, stream>>>(
        m2, hprev,
        (const float4*)(WfA + (size_t)t * HDIM * 64 * 4),
        (const float2*)(WfB + (size_t)t * HDIM * 64 * 2),
        (const float4*)WhA, (const float2*)WhB,
        bfb + t * H3, bh, Waw, baw, hcur, out, sden, mxv, NNODES);
  }

  attn_finalize<<<(NNODES * HDIM + 255) / 256, 256, 0, stream>>>(out, sden);
}

// Round 7
// 3058.463 us; speedup vs baseline: 6.1885x; 1.4778x over previous
//
#include <hip/hip_runtime.h>
#include <hip/hip_bf16.h>

#define NNODES 50000
#define TSTEPS 8
#define NEDGES 800000
#define VVOCAB 1000
#define DDIM 32
#define HDIM 128
#define G0DIM 64
#define H3 384

typedef _Float16 v8h __attribute__((ext_vector_type(8)));
typedef float v4f __attribute__((ext_vector_type(4)));

// ---------------- zero fill for int counters ---------------------------------------------
__global__ __launch_bounds__(256) void fill_zero_int(int* __restrict__ p, int n) {
  int i = blockIdx.x * 256 + threadIdx.x;
  if (i < n) p[i] = 0;
}

// ---------------- CSR build: histogram ----------------------------------------------------
__global__ __launch_bounds__(256) void hist_dst(const int* __restrict__ e_dst,
                                                int* __restrict__ deg) {
  int e = blockIdx.x * 256 + threadIdx.x;
  if (e < NEDGES) atomicAdd(&deg[e_dst[e]], 1);
}

// ---------------- CSR build: single-block scan --------------------------------------------
__global__ __launch_bounds__(1024) void scan_deg(const int* __restrict__ deg,
                                                 int* __restrict__ off,
                                                 int* __restrict__ cursor) {
  const int T = 1024;
  const int CH = (NNODES + T - 1) / T;
  int t = threadIdx.x;
  int start = t * CH;
  int end = min(start + CH, NNODES);
  __shared__ int buf[T];
  int s = 0;
  for (int i = start; i < end; ++i) s += deg[i];
  buf[t] = s;
  __syncthreads();
  for (int d = 1; d < T; d <<= 1) {
    int v = (t >= d) ? buf[t - d] : 0;
    __syncthreads();
    buf[t] += v;
    __syncthreads();
  }
  int pre = (t == 0) ? 0 : buf[t - 1];
  for (int i = start; i < end; ++i) {
    off[i] = pre;
    cursor[i] = pre;
    pre += deg[i];
  }
  if (t == T - 1) off[NNODES] = buf[T - 1];
}

// ---------------- CSR build: bucket fill ---------------------------------------------------
__global__ __launch_bounds__(256) void fill_csr(
    const int* __restrict__ e_src, const int* __restrict__ e_dst,
    const float* __restrict__ w, int* __restrict__ cursor,
    int2* __restrict__ csr) {
  int e = blockIdx.x * 256 + threadIdx.x;
  if (e >= NEDGES) return;
  int d = e_dst[e];
  int pos = atomicAdd(&cursor[d], 1);
  int2 pk;
  pk.x = e_src[e];
  pk.y = __float_as_int(w[e]);
  csr[pos] = pk;
}

// ---------------- pull aggregation fp32 (D=64), 4-edge unrolled ---------------------------
template <int D, int LPN>
__global__ __launch_bounds__(256) void gather_agg(
    const int* __restrict__ off, const int2* __restrict__ csr,
    const float* __restrict__ x, float* __restrict__ m) {
  const int NPB = 256 / LPN;
  int n = blockIdx.x * NPB + threadIdx.x / LPN;
  int l = threadIdx.x % LPN;
  if (n >= NNODES) return;
  int s0 = off[n], s1 = off[n + 1];
  float a0x = 0.f, a0y = 0.f, a0z = 0.f, a0w = 0.f;
  float a1x = 0.f, a1y = 0.f, a1z = 0.f, a1w = 0.f;
  int e = s0;
  for (; e + 3 < s1; e += 4) {
    int2 e0 = csr[e], e1 = csr[e + 1], e2 = csr[e + 2], e3 = csr[e + 3];
    float4 x0 = *(const float4*)&x[(size_t)e0.x * D + l * 4];
    float4 x1 = *(const float4*)&x[(size_t)e1.x * D + l * 4];
    float4 x2 = *(const float4*)&x[(size_t)e2.x * D + l * 4];
    float4 x3 = *(const float4*)&x[(size_t)e3.x * D + l * 4];
    float w0 = __int_as_float(e0.y), w1 = __int_as_float(e1.y);
    float w2 = __int_as_float(e2.y), w3 = __int_as_float(e3.y);
    a0x += w0 * x0.x + w2 * x2.x; a0y += w0 * x0.y + w2 * x2.y;
    a0z += w0 * x0.z + w2 * x2.z; a0w += w0 * x0.w + w2 * x2.w;
    a1x += w1 * x1.x + w3 * x3.x; a1y += w1 * x1.y + w3 * x3.y;
    a1z += w1 * x1.z + w3 * x3.z; a1w += w1 * x1.w + w3 * x3.w;
  }
  for (; e < s1; ++e) {
    int2 eA = csr[e];
    float4 xA = *(const float4*)&x[(size_t)eA.x * D + l * 4];
    float wA = __int_as_float(eA.y);
    a0x += wA * xA.x; a0y += wA * xA.y; a0z += wA * xA.z; a0w += wA * xA.w;
  }
  float4 r;
  r.x = a0x + a1x; r.y = a0y + a1y; r.z = a0z + a1z; r.w = a0w + a1w;
  *(float4*)&m[(size_t)n * D + l * 4] = r;
}

// ---------------- pull aggregation fp16 (D=128): 16 lanes x 8 halves ----------------------
__global__ __launch_bounds__(256) void gather_agg_h(
    const int* __restrict__ off, const int2* __restrict__ csr,
    const _Float16* __restrict__ x, _Float16* __restrict__ m) {
  int n = blockIdx.x * 16 + (threadIdx.x >> 4);
  int l = threadIdx.x & 15;
  if (n >= NNODES) return;
  int s0 = off[n], s1 = off[n + 1];
  float a0[8], a1[8];
#pragma unroll
  for (int i = 0; i < 8; ++i) { a0[i] = 0.f; a1[i] = 0.f; }
  int e = s0;
  for (; e + 1 < s1; e += 2) {
    int2 eA = csr[e], eB = csr[e + 1];
    v8h xA = *(const v8h*)&x[(size_t)eA.x * HDIM + l * 8];
    v8h xB = *(const v8h*)&x[(size_t)eB.x * HDIM + l * 8];
    float wA = __int_as_float(eA.y), wB = __int_as_float(eB.y);
#pragma unroll
    for (int i = 0; i < 8; ++i) {
      a0[i] += wA * (float)xA[i];
      a1[i] += wB * (float)xB[i];
    }
  }
  if (e < s1) {
    int2 eA = csr[e];
    v8h xA = *(const v8h*)&x[(size_t)eA.x * HDIM + l * 8];
    float wA = __int_as_float(eA.y);
#pragma unroll
    for (int i = 0; i < 8; ++i) a0[i] += wA * (float)xA[i];
  }
  v8h r;
#pragma unroll
  for (int i = 0; i < 8; ++i) r[i] = (_Float16)(a0[i] + a1[i]);
  *(v8h*)&m[(size_t)n * HDIM + l * 8] = r;
}

// ---- fused weight precompute: Wf32[t] = W2_t @ Wx ([128,128]@[128,384]) ------------------
__global__ __launch_bounds__(384) void fuse_w(
    const float* __restrict__ gW2, const float* __restrict__ Wx, float* __restrict__ Wf) {
  int t = blockIdx.x >> 7;
  int k = blockIdx.x & 127;
  int j = threadIdx.x;
  __shared__ float row[HDIM];
  if (j < HDIM) row[j] = gW2[((size_t)t * HDIM + k) * HDIM + j];
  __syncthreads();
  float acc = 0.f;
#pragma unroll 8
  for (int c = 0; c < HDIM; ++c) acc += row[c] * Wx[c * H3 + j];
  Wf[((size_t)t * HDIM + k) * H3 + j] = acc;
}

// ---- fused bias precompute: bf[t] = b2_t @ Wx + bx ---------------------------------------
__global__ __launch_bounds__(384) void fuse_b(
    const float* __restrict__ gb2, const float* __restrict__ Wx,
    const float* __restrict__ bx, float* __restrict__ bf) {
  int t = blockIdx.x;
  int j = threadIdx.x;
  __shared__ float row[HDIM];
  if (j < HDIM) row[j] = gb2[t * HDIM + j];
  __syncthreads();
  float acc = bx[j];
#pragma unroll 8
  for (int c = 0; c < HDIM; ++c) acc += row[c] * Wx[c * H3 + j];
  bf[t * H3 + j] = acc;
}

// ---- pack combined transposed fp16 weights: Wcombt[t][col(512)][k(256)] ------------------
// cols 0:256 -> r,z sums (Wf top / Wh bottom); 256:384 -> xn (Wf only); 384:512 -> hn (Wh only)
__global__ __launch_bounds__(256) void pack_wcomb(
    const float* __restrict__ Wf32, const float* __restrict__ Wh,
    _Float16* __restrict__ Wcombt) {
  int t = blockIdx.x >> 9;
  int col = blockIdx.x & 511;
  int k = threadIdx.x;  // 0..255
  float v;
  if (col < 384) {
    if (k < 128) v = Wf32[((size_t)t * HDIM + k) * H3 + col];
    else v = (col < 256) ? Wh[(size_t)(k - 128) * H3 + col] : 0.f;
  } else {
    v = (k < 128) ? 0.f : Wh[(size_t)(k - 128) * H3 + (col - 128)];
  }
  Wcombt[((size_t)t * 512 + col) * 256 + k] = (_Float16)v;
}

// ---- pack combined bias: bcomb[t][512] ----------------------------------------------------
__global__ __launch_bounds__(512) void pack_bcomb(
    const float* __restrict__ bfb, const float* __restrict__ bh,
    float* __restrict__ bcomb) {
  int t = blockIdx.x;
  int c = threadIdx.x;  // 0..511
  float v;
  if (c < 256) v = bfb[t * H3 + c] + bh[c];
  else if (c < 384) v = bfb[t * H3 + c];
  else v = bh[c - 128];
  bcomb[t * 512 + c] = v;
}

// ---- static encoder + attention init ------------------------------------------------------
__global__ __launch_bounds__(128) void static_encode_attn_init(
    const float* __restrict__ dense, const int* __restrict__ sparse,
    const float* __restrict__ emb,
    const float* __restrict__ Ws, const float* __restrict__ bs,
    const float* __restrict__ Waw, const float* __restrict__ baw,
    float* __restrict__ acc, float* __restrict__ s, float* __restrict__ mx) {
  int n = blockIdx.x;
  int j = threadIdx.x;
  __shared__ float xs[G0DIM];
  if (j < G0DIM) {
    float v;
    if (j < 16) {
      v = emb[sparse[n * 2 + 0] * 16 + j];
    } else if (j < 32) {
      v = emb[VVOCAB * 16 + sparse[n * 2 + 1] * 16 + (j - 16)];
    } else {
      v = dense[n * DDIM + (j - 32)];
    }
    xs[j] = v;
  }
  __syncthreads();
  float a = bs[j];
#pragma unroll 16
  for (int k = 0; k < G0DIM; ++k) a += xs[k] * Ws[k * HDIM + j];
  a = fmaxf(a, 0.f);
  float v = tanhf(a) * Waw[j];
  __shared__ float red[2];
  int lane = j & 63, wid = j >> 6;
#pragma unroll
  for (int off = 32; off > 0; off >>= 1) v += __shfl_down(v, off, 64);
  if (lane == 0) red[wid] = v;
  __syncthreads();
  acc[(size_t)n * HDIM + j] = a;
  if (j == 0) {
    s[n] = 1.f;
    mx[n] = red[0] + red[1] + baw[0];
  }
}

// ---------------- dynamic feature gather, float4 per thread ------------------------------
__global__ __launch_bounds__(256) void dynx_gather4(
    const float* __restrict__ dense_t, const int* __restrict__ sparse_t,
    const float* __restrict__ emb, float4* __restrict__ xout) {
  int idx = blockIdx.x * 256 + threadIdx.x;
  int n = idx >> 4, k4 = idx & 15;
  if (n >= NNODES) return;
  float4 v;
  if (k4 < 4)
    v = *(const float4*)&emb[sparse_t[n * 2 + 0] * 16 + k4 * 4];
  else if (k4 < 8)
    v = *(const float4*)&emb[VVOCAB * 16 + sparse_t[n * 2 + 1] * 16 + (k4 - 4) * 4];
  else
    v = *(const float4*)&dense_t[n * DDIM + (k4 - 8) * 4];
  xout[idx] = v;
}

// ---------------- row matmul (fp16 out): 64 thr, NB=8 nodes, 2 cols/thread ----------------
__global__ __launch_bounds__(64) void rowmm64(
    const float* __restrict__ x, const float* __restrict__ W,
    const float* __restrict__ b, _Float16* __restrict__ y) {
  const int NB = 8;
  int n0 = blockIdx.x * NB;
  int j = threadIdx.x;
  __shared__ float xT[G0DIM][12];
#pragma unroll
  for (int q = 0; q < NB; ++q) xT[j][q] = x[(size_t)(n0 + q) * G0DIM + j];
  __syncthreads();
  float acc0[NB], acc1[NB];
#pragma unroll
  for (int q = 0; q < NB; ++q) { acc0[q] = 0.f; acc1[q] = 0.f; }
#pragma unroll 4
  for (int k = 0; k < G0DIM; ++k) {
    float4 a = *(const float4*)&xT[k][0];
    float4 c = *(const float4*)&xT[k][4];
    float w0 = W[(size_t)k * HDIM + j];
    float w1 = W[(size_t)k * HDIM + j + 64];
    acc0[0] += a.x * w0; acc0[1] += a.y * w0; acc0[2] += a.z * w0; acc0[3] += a.w * w0;
    acc0[4] += c.x * w0; acc0[5] += c.y * w0; acc0[6] += c.z * w0; acc0[7] += c.w * w0;
    acc1[0] += a.x * w1; acc1[1] += a.y * w1; acc1[2] += a.z * w1; acc1[3] += a.w * w1;
    acc1[4] += c.x * w1; acc1[5] += c.y * w1; acc1[6] += c.z * w1; acc1[7] += c.w * w1;
  }
  float b0 = b[j], b1 = b[j + 64];
#pragma unroll
  for (int q = 0; q < NB; ++q) {
    y[(size_t)(n0 + q) * HDIM + j] = (_Float16)fmaxf(acc0[q] + b0, 0.f);
    y[(size_t)(n0 + q) * HDIM + j + 64] = (_Float16)fmaxf(acc1[q] + b1, 0.f);
  }
}

__device__ __forceinline__ float sigmoidf_(float v) {
  return 1.f / (1.f + expf(-v));
}

// ---------------- MFMA GRU + attention: 32 nodes/block, 4 waves ---------------------------
// A = [Xh | Hp] (32 x 256 fp16 in LDS), B = Wcombt (512 cols x 256 k fp16, global/L2).
// Wave w owns N-tiles {g*8 + 2w + p : g=0..3, p=0..1} -> out cols j in [32w, 32w+32) for
// all 4 gate groups. D frag: row=(lane>>4)*4+reg, col=lane&15.
__global__ __launch_bounds__(256) void gru_mfma(
    const _Float16* __restrict__ Xh, const _Float16* __restrict__ Hp,
    const _Float16* __restrict__ Bt, const float* __restrict__ bcomb,
    const float* __restrict__ Waw, const float* __restrict__ baw,
    _Float16* __restrict__ hout, float* __restrict__ acc,
    float* __restrict__ sden, float* __restrict__ mxv) {
  const int AST = 264;  // A row stride in halves (528 B, 16B-aligned)
  __shared__ _Float16 A_lds[32 * AST];
  __shared__ float h_lds[32 * 132];
  __shared__ float lg[32], facs[32], ps[32];
  int tid = threadIdx.x;
  int w = tid >> 6, lane = tid & 63;
  int n0 = blockIdx.x * 32;

  // stage A rows: 32 rows x 32 chunks of 8 halves
#pragma unroll
  for (int i = 0; i < 4; ++i) {
    int cid = tid + i * 256;
    int row = cid >> 5, ch = cid & 31;
    int n = n0 + row;
    v8h v = {(_Float16)0, (_Float16)0, (_Float16)0, (_Float16)0,
             (_Float16)0, (_Float16)0, (_Float16)0, (_Float16)0};
    if (n < NNODES) {
      if (ch < 16) v = *(const v8h*)&Xh[(size_t)n * HDIM + ch * 8];
      else if (Hp) v = *(const v8h*)&Hp[(size_t)n * HDIM + (ch - 16) * 8];
    }
    *(v8h*)&A_lds[row * AST + ch * 8] = v;
  }
  __syncthreads();

  int lj = lane & 15, lr = lane >> 4;
  v4f accf[2][8];
#pragma unroll
  for (int m = 0; m < 2; ++m)
#pragma unroll
    for (int f = 0; f < 8; ++f) accf[m][f] = (v4f){0.f, 0.f, 0.f, 0.f};

  for (int ks = 0; ks < 8; ++ks) {
    v8h a0 = *(const v8h*)&A_lds[lj * AST + ks * 32 + lr * 8];
    v8h a1 = *(const v8h*)&A_lds[(16 + lj) * AST + ks * 32 + lr * 8];
#pragma unroll
    for (int g = 0; g < 4; ++g)
#pragma unroll
      for (int p = 0; p < 2; ++p) {
        int col = (g * 8 + w * 2 + p) * 16 + lj;
        v8h b = *(const v8h*)&Bt[(size_t)col * 256 + ks * 32 + lr * 8];
        accf[0][g * 2 + p] =
            __builtin_amdgcn_mfma_f32_16x16x32_f16(a0, b, accf[0][g * 2 + p], 0, 0, 0);
        accf[1][g * 2 + p] =
            __builtin_amdgcn_mfma_f32_16x16x32_f16(a1, b, accf[1][g * 2 + p], 0, 0, 0);
      }
  }

  // epilogue: gates -> h (fp32) into h_lds
#pragma unroll
  for (int p = 0; p < 2; ++p) {
    int j = (w * 2 + p) * 16 + lj;
    float br = bcomb[j], bz = bcomb[128 + j], bxn = bcomb[256 + j], bhn = bcomb[384 + j];
#pragma unroll
    for (int m = 0; m < 2; ++m)
#pragma unroll
      for (int reg = 0; reg < 4; ++reg) {
        int row = m * 16 + lr * 4 + reg;
        float r = sigmoidf_(accf[m][0 + p][reg] + br);
        float z = sigmoidf_(accf[m][2 + p][reg] + bz);
        float hp = (float)A_lds[row * AST + 128 + j];
        float nc = tanhf(accf[m][4 + p][reg] + bxn + r * (accf[m][6 + p][reg] + bhn));
        h_lds[row * 132 + j] = (1.f - z) * nc + z * hp;
      }
  }
  __syncthreads();

  // attention logits: wave w reduces nodes w*8 .. w*8+7
  float waw0 = Waw[lane], waw1 = Waw[lane + 64];
#pragma unroll
  for (int q = 0; q < 8; ++q) {
    int row = w * 8 + q;
    float v = tanhf(h_lds[row * 132 + lane]) * waw0 +
              tanhf(h_lds[row * 132 + lane + 64]) * waw1;
#pragma unroll
    for (int off = 32; off > 0; off >>= 1) v += __shfl_down(v, off, 64);
    if (lane == 0) lg[row] = v;
  }
  __syncthreads();
  if (tid < 32) {
    int n = n0 + tid;
    if (n < NNODES) {
      float l = lg[tid] + baw[0];
      float m = mxv[n];
      float mnew = fmaxf(m, l);
      float fac = expf(m - mnew);
      float pp = expf(l - mnew);
      facs[tid] = fac;
      ps[tid] = pp;
      sden[n] = sden[n] * fac + pp;
      mxv[n] = mnew;
    }
  }
  __syncthreads();
  // coalesced acc update + fp16 h write
#pragma unroll
  for (int i = 0; i < 16; ++i) {
    int idx = tid + i * 256;  // 32*128
    int row = idx >> 7, col = idx & 127;
    int n = n0 + row;
    if (n < NNODES) {
      float hv = h_lds[row * 132 + col];
      size_t o = (size_t)n * HDIM + col;
      acc[o] = acc[o] * facs[row] + ps[row] * hv;
      hout[o] = (_Float16)hv;
    }
  }
}

// ---- finalize: out /= s ------------------------------------------------------------------
__global__ __launch_bounds__(256) void attn_finalize(
    float* __restrict__ acc, const float* __restrict__ s) {
  int idx = blockIdx.x * 256 + threadIdx.x;
  if (idx >= NNODES * HDIM) return;
  acc[idx] = acc[idx] / s[idx >> 7];
}

extern "C" void kernel_launch(void* const* d_in, const int* in_sizes, int n_in,
                              void* d_out, int out_size, void* d_ws, size_t ws_size,
                              hipStream_t stream) {
  const float* static_dense = (const float*)d_in[0];
  const int*   static_sparse = (const int*)d_in[1];
  const float* dyn_dense = (const float*)d_in[2];
  const int*   dyn_sparse = (const int*)d_in[3];
  const int*   edges = (const int*)d_in[4];
  const float* weights = (const float*)d_in[5];
  const float* s_emb = (const float*)d_in[6];
  const float* d_emb = (const float*)d_in[7];
  const float* Ws = (const float*)d_in[8];
  const float* bs = (const float*)d_in[9];
  const float* gW1 = (const float*)d_in[10];
  const float* gb1 = (const float*)d_in[11];
  const float* gW2 = (const float*)d_in[12];
  const float* gb2 = (const float*)d_in[13];
  const float* Wx = (const float*)d_in[14];
  const float* Wh = (const float*)d_in[15];
  const float* bx = (const float*)d_in[16];
  const float* bh = (const float*)d_in[17];
  const float* Waw = (const float*)d_in[18];
  const float* baw = (const float*)d_in[19];
  float* out = (float*)d_out;  // attention accumulator [N,128] fp32

  const size_t N = NNODES;
  char* p = (char*)d_ws;
  auto alloc = [&](size_t bytes) { char* r = p; p += (bytes + 255) & ~(size_t)255; return r; };
  float*     sden   = (float*)alloc(N * 4);
  float*     mxv    = (float*)alloc(N * 4);
  _Float16*  hA     = (_Float16*)alloc(N * HDIM * 2);
  _Float16*  hB     = (_Float16*)alloc(N * HDIM * 2);
  float*     R1     = (float*)alloc(N * HDIM * 4);  // dynx(N*64) | m1(N*64)
  _Float16*  h1h    = (_Float16*)alloc(N * HDIM * 2);
  _Float16*  Xh     = (_Float16*)alloc(N * HDIM * 2);
  float*     Wf32   = (float*)alloc((size_t)TSTEPS * HDIM * H3 * 4);
  _Float16*  Wcombt = (_Float16*)alloc((size_t)TSTEPS * 512 * 256 * 2);
  float*     bfb    = (float*)alloc((size_t)TSTEPS * H3 * 4);
  float*     bcomb  = (float*)alloc((size_t)TSTEPS * 512 * 4);
  int*       deg    = (int*)alloc(N * 4);
  int*       offs   = (int*)alloc((N + 1) * 4);
  int*       cursor = (int*)alloc(N * 4);
  int2*      csr    = (int2*)alloc((size_t)NEDGES * 8);
  float*     dynx   = R1;
  float*     m1     = R1 + N * G0DIM;

  fuse_w<<<TSTEPS * HDIM, H3, 0, stream>>>(gW2, Wx, Wf32);
  fuse_b<<<TSTEPS, H3, 0, stream>>>(gb2, Wx, bx, bfb);
  pack_wcomb<<<TSTEPS * 512, 256, 0, stream>>>(Wf32, Wh, Wcombt);
  pack_bcomb<<<TSTEPS, 512, 0, stream>>>(bfb, bh, bcomb);

  static_encode_attn_init<<<NNODES, 128, 0, stream>>>(
      static_dense, static_sparse, s_emb, Ws, bs, Waw, baw, out, sden, mxv);

  const int EB = (NEDGES + 255) / 256;
  const int GRUB = (NNODES + 31) / 32;
  for (int t = 0; t < TSTEPS; ++t) {
    const int* e_src = edges + (size_t)t * 2 * NEDGES;
    const int* e_dst = e_src + NEDGES;
    const float* w_t = weights + (size_t)t * NEDGES;
    _Float16* hcur = (t & 1) ? hB : hA;
    const _Float16* hprev = (t == 0) ? nullptr : ((t & 1) ? hA : hB);

    fill_zero_int<<<(NNODES + 255) / 256, 256, 0, stream>>>(deg, NNODES);
    hist_dst<<<EB, 256, 0, stream>>>(e_dst, deg);
    scan_deg<<<1, 1024, 0, stream>>>(deg, offs, cursor);
    fill_csr<<<EB, 256, 0, stream>>>(e_src, e_dst, w_t, cursor, csr);

    dynx_gather4<<<(NNODES * 16 + 255) / 256, 256, 0, stream>>>(
        dyn_dense + (size_t)t * N * DDIM, dyn_sparse + (size_t)t * N * 2, d_emb,
        (float4*)dynx);

    gather_agg<G0DIM, 16><<<(NNODES + 15) / 16, 256, 0, stream>>>(offs, csr, dynx, m1);

    rowmm64<<<NNODES / 8, 64, 0, stream>>>(
        m1, gW1 + (size_t)t * G0DIM * HDIM, gb1 + (size_t)t * HDIM, h1h);

    gather_agg_h<<<(NNODES + 15) / 16, 256, 0, stream>>>(offs, csr, h1h, Xh);

    gru_mfma<<<GRUB, 256, 0, stream>>>(
        Xh, hprev, Wcombt + (size_t)t * 512 * 256, bcomb + t * 512,
        Waw, baw, hcur, out, sden, mxv);
  }

  attn_finalize<<<(NNODES * HDIM + 255) / 256, 256, 0, stream>>>(out, sden);
}

// Round 8
// 2037.850 us; speedup vs baseline: 9.2879x; 1.5008x over previous
//
#include <hip/hip_runtime.h>
#include <hip/hip_bf16.h>

#define NNODES 50000
#define TSTEPS 8
#define NEDGES 800000
#define VVOCAB 1000
#define DDIM 32
#define HDIM 128
#define G0DIM 64
#define H3 384
#define NCH 98  // ceil(NNODES/512) chunks per timestep

typedef _Float16 v8h __attribute__((ext_vector_type(8)));
typedef float v4f __attribute__((ext_vector_type(4)));

// ---------------- zero fill for int counters ---------------------------------------------
__global__ __launch_bounds__(256) void fill_zero_int(int* __restrict__ p, int n) {
  int i = blockIdx.x * 256 + threadIdx.x;
  if (i < n) p[i] = 0;
}

// ---------------- batched histogram over all timesteps ------------------------------------
__global__ __launch_bounds__(256) void hist_all(const int* __restrict__ edges,
                                                int* __restrict__ deg) {
  long long i = (long long)blockIdx.x * 256 + threadIdx.x;
  if (i >= (long long)TSTEPS * NEDGES) return;
  int t = (int)(i / NEDGES), e = (int)(i % NEDGES);
  int dst = edges[(size_t)t * 2 * NEDGES + NEDGES + e];
  atomicAdd(&deg[t * NNODES + dst], 1);
}

// ---------------- hierarchical scan: K1 chunk sums ----------------------------------------
__global__ __launch_bounds__(256) void scan_k1(const int* __restrict__ deg,
                                               int* __restrict__ csum) {
  int bid = blockIdx.x;  // t*NCH + c
  int t = bid / NCH, c = bid % NCH;
  int tid = threadIdx.x;
  int s = 0;
#pragma unroll
  for (int i = 0; i < 2; ++i) {
    int n = c * 512 + tid + i * 256;
    if (n < NNODES) s += deg[t * NNODES + n];
  }
#pragma unroll
  for (int off = 32; off > 0; off >>= 1) s += __shfl_down(s, off, 64);
  __shared__ int wsum[4];
  if ((tid & 63) == 0) wsum[tid >> 6] = s;
  __syncthreads();
  if (tid == 0) csum[bid] = wsum[0] + wsum[1] + wsum[2] + wsum[3];
}

// ---------------- K2: per-t exclusive scan of 98 chunk sums -------------------------------
__global__ __launch_bounds__(128) void scan_k2(const int* __restrict__ csum,
                                               int* __restrict__ cbase,
                                               int* __restrict__ off) {
  int t = blockIdx.x;
  int tid = threadIdx.x;
  __shared__ int buf[128];
  int own = (tid < NCH) ? csum[t * NCH + tid] : 0;
  buf[tid] = own;
  __syncthreads();
  for (int d = 1; d < 128; d <<= 1) {
    int v = (tid >= d) ? buf[tid - d] : 0;
    __syncthreads();
    buf[tid] += v;
    __syncthreads();
  }
  if (tid < NCH) cbase[t * NCH + tid] = buf[tid] - own;
  if (tid == 0) off[(size_t)t * (NNODES + 1) + NNODES] = NEDGES;
}

// ---------------- K3: in-chunk exclusive scan + base -> off, cursor -----------------------
__global__ __launch_bounds__(512) void scan_k3(const int* __restrict__ deg,
                                               const int* __restrict__ cbase,
                                               int* __restrict__ off,
                                               int* __restrict__ cursor) {
  int bid = blockIdx.x;
  int t = bid / NCH, c = bid % NCH;
  int tid = threadIdx.x;
  int n = c * 512 + tid;
  int d = (n < NNODES) ? deg[t * NNODES + n] : 0;
  __shared__ int buf[512];
  buf[tid] = d;
  __syncthreads();
  for (int s = 1; s < 512; s <<= 1) {
    int v = (tid >= s) ? buf[tid - s] : 0;
    __syncthreads();
    buf[tid] += v;
    __syncthreads();
  }
  if (n < NNODES) {
    int ex = cbase[bid] + buf[tid] - d;
    off[(size_t)t * (NNODES + 1) + n] = ex;
    cursor[t * NNODES + n] = ex;
  }
}

// ---------------- CSR build: bucket fill ---------------------------------------------------
__global__ __launch_bounds__(256) void fill_csr(
    const int* __restrict__ e_src, const int* __restrict__ e_dst,
    const float* __restrict__ w, int* __restrict__ cursor,
    int2* __restrict__ csr) {
  int e = blockIdx.x * 256 + threadIdx.x;
  if (e >= NEDGES) return;
  int d = e_dst[e];
  int pos = atomicAdd(&cursor[d], 1);
  int2 pk;
  pk.x = e_src[e];
  pk.y = __float_as_int(w[e]);
  csr[pos] = pk;
}

// ---------------- pull aggregation fp16, D halves/row, 8 halves/lane ----------------------
template <int D>
__global__ __launch_bounds__(256) void gather_agg_h(
    const int* __restrict__ off, const int2* __restrict__ csr,
    const _Float16* __restrict__ x, _Float16* __restrict__ m) {
  const int LPN = D / 8;
  int n = blockIdx.x * (256 / LPN) + threadIdx.x / LPN;
  int l = threadIdx.x % LPN;
  if (n >= NNODES) return;
  int s0 = off[n], s1 = off[n + 1];
  float a0[8], a1[8];
#pragma unroll
  for (int i = 0; i < 8; ++i) { a0[i] = 0.f; a1[i] = 0.f; }
  int e = s0;
  for (; e + 1 < s1; e += 2) {
    int2 eA = csr[e], eB = csr[e + 1];
    v8h xA = *(const v8h*)&x[(size_t)eA.x * D + l * 8];
    v8h xB = *(const v8h*)&x[(size_t)eB.x * D + l * 8];
    float wA = __int_as_float(eA.y), wB = __int_as_float(eB.y);
#pragma unroll
    for (int i = 0; i < 8; ++i) {
      a0[i] += wA * (float)xA[i];
      a1[i] += wB * (float)xB[i];
    }
  }
  if (e < s1) {
    int2 eA = csr[e];
    v8h xA = *(const v8h*)&x[(size_t)eA.x * D + l * 8];
    float wA = __int_as_float(eA.y);
#pragma unroll
    for (int i = 0; i < 8; ++i) a0[i] += wA * (float)xA[i];
  }
  v8h r;
#pragma unroll
  for (int i = 0; i < 8; ++i) r[i] = (_Float16)(a0[i] + a1[i]);
  *(v8h*)&m[(size_t)n * D + l * 8] = r;
}

// ---- fused weight precompute: Wf32[t] = W2_t @ Wx ([128,128]@[128,384]) ------------------
__global__ __launch_bounds__(384) void fuse_w(
    const float* __restrict__ gW2, const float* __restrict__ Wx, float* __restrict__ Wf) {
  int t = blockIdx.x >> 7;
  int k = blockIdx.x & 127;
  int j = threadIdx.x;
  __shared__ float row[HDIM];
  if (j < HDIM) row[j] = gW2[((size_t)t * HDIM + k) * HDIM + j];
  __syncthreads();
  float acc = 0.f;
#pragma unroll 8
  for (int c = 0; c < HDIM; ++c) acc += row[c] * Wx[c * H3 + j];
  Wf[((size_t)t * HDIM + k) * H3 + j] = acc;
}

// ---- fused bias precompute: bf[t] = b2_t @ Wx + bx ---------------------------------------
__global__ __launch_bounds__(384) void fuse_b(
    const float* __restrict__ gb2, const float* __restrict__ Wx,
    const float* __restrict__ bx, float* __restrict__ bf) {
  int t = blockIdx.x;
  int j = threadIdx.x;
  __shared__ float row[HDIM];
  if (j < HDIM) row[j] = gb2[t * HDIM + j];
  __syncthreads();
  float acc = bx[j];
#pragma unroll 8
  for (int c = 0; c < HDIM; ++c) acc += row[c] * Wx[c * H3 + j];
  bf[t * H3 + j] = acc;
}

// ---- pack combined transposed fp16 weights: Wcombt[t][col(512)][k(256)] ------------------
__global__ __launch_bounds__(256) void pack_wcomb(
    const float* __restrict__ Wf32, const float* __restrict__ Wh,
    _Float16* __restrict__ Wcombt) {
  int t = blockIdx.x >> 9;
  int col = blockIdx.x & 511;
  int k = threadIdx.x;  // 0..255
  float v;
  if (col < 384) {
    if (k < 128) v = Wf32[((size_t)t * HDIM + k) * H3 + col];
    else v = (col < 256) ? Wh[(size_t)(k - 128) * H3 + col] : 0.f;
  } else {
    v = (k < 128) ? 0.f : Wh[(size_t)(k - 128) * H3 + (col - 128)];
  }
  Wcombt[((size_t)t * 512 + col) * 256 + k] = (_Float16)v;
}

// ---- pack combined bias: bcomb[t][512] ----------------------------------------------------
__global__ __launch_bounds__(512) void pack_bcomb(
    const float* __restrict__ bfb, const float* __restrict__ bh,
    float* __restrict__ bcomb) {
  int t = blockIdx.x;
  int c = threadIdx.x;
  float v;
  if (c < 256) v = bfb[t * H3 + c] + bh[c];
  else if (c < 384) v = bfb[t * H3 + c];
  else v = bh[c - 128];
  bcomb[t * 512 + c] = v;
}

// ---- static encoder + attention init ------------------------------------------------------
__global__ __launch_bounds__(128) void static_encode_attn_init(
    const float* __restrict__ dense, const int* __restrict__ sparse,
    const float* __restrict__ emb,
    const float* __restrict__ Ws, const float* __restrict__ bs,
    const float* __restrict__ Waw, const float* __restrict__ baw,
    float* __restrict__ acc, float* __restrict__ s, float* __restrict__ mx) {
  int n = blockIdx.x;
  int j = threadIdx.x;
  __shared__ float xs[G0DIM];
  if (j < G0DIM) {
    float v;
    if (j < 16) {
      v = emb[sparse[n * 2 + 0] * 16 + j];
    } else if (j < 32) {
      v = emb[VVOCAB * 16 + sparse[n * 2 + 1] * 16 + (j - 16)];
    } else {
      v = dense[n * DDIM + (j - 32)];
    }
    xs[j] = v;
  }
  __syncthreads();
  float a = bs[j];
#pragma unroll 16
  for (int k = 0; k < G0DIM; ++k) a += xs[k] * Ws[k * HDIM + j];
  a = fmaxf(a, 0.f);
  float v = tanhf(a) * Waw[j];
  __shared__ float red[2];
  int lane = j & 63, wid = j >> 6;
#pragma unroll
  for (int off = 32; off > 0; off >>= 1) v += __shfl_down(v, off, 64);
  if (lane == 0) red[wid] = v;
  __syncthreads();
  acc[(size_t)n * HDIM + j] = a;
  if (j == 0) {
    s[n] = 1.f;
    mx[n] = red[0] + red[1] + baw[0];
  }
}

// ---------------- dynamic feature gather -> fp16, 8 halves/thread -------------------------
__global__ __launch_bounds__(256) void dynx_gather_h(
    const float* __restrict__ dense_t, const int* __restrict__ sparse_t,
    const float* __restrict__ emb, _Float16* __restrict__ xout) {
  int idx = blockIdx.x * 256 + threadIdx.x;  // over N*8
  int n = idx >> 3, k8 = idx & 7;
  if (n >= NNODES) return;
  const float* src;
  if (k8 < 2)
    src = &emb[sparse_t[n * 2 + 0] * 16 + k8 * 8];
  else if (k8 < 4)
    src = &emb[VVOCAB * 16 + sparse_t[n * 2 + 1] * 16 + (k8 - 2) * 8];
  else
    src = &dense_t[n * DDIM + (k8 - 4) * 8];
  float4 f0 = *(const float4*)src;
  float4 f1 = *(const float4*)(src + 4);
  v8h v = {(_Float16)f0.x, (_Float16)f0.y, (_Float16)f0.z, (_Float16)f0.w,
           (_Float16)f1.x, (_Float16)f1.y, (_Float16)f1.z, (_Float16)f1.w};
  *(v8h*)&xout[(size_t)n * G0DIM + k8 * 8] = v;
}

// ---------------- row matmul (fp16 in/out): 64 thr, NB=8 nodes, 2 cols/thread -------------
__global__ __launch_bounds__(64) void rowmm64(
    const _Float16* __restrict__ x, const float* __restrict__ W,
    const float* __restrict__ b, _Float16* __restrict__ y) {
  const int NB = 8;
  int n0 = blockIdx.x * NB;
  int j = threadIdx.x;
  __shared__ float xT[G0DIM][12];
#pragma unroll
  for (int q = 0; q < NB; ++q) xT[j][q] = (float)x[(size_t)(n0 + q) * G0DIM + j];
  __syncthreads();
  float acc0[NB], acc1[NB];
#pragma unroll
  for (int q = 0; q < NB; ++q) { acc0[q] = 0.f; acc1[q] = 0.f; }
#pragma unroll 4
  for (int k = 0; k < G0DIM; ++k) {
    float4 a = *(const float4*)&xT[k][0];
    float4 c = *(const float4*)&xT[k][4];
    float w0 = W[(size_t)k * HDIM + j];
    float w1 = W[(size_t)k * HDIM + j + 64];
    acc0[0] += a.x * w0; acc0[1] += a.y * w0; acc0[2] += a.z * w0; acc0[3] += a.w * w0;
    acc0[4] += c.x * w0; acc0[5] += c.y * w0; acc0[6] += c.z * w0; acc0[7] += c.w * w0;
    acc1[0] += a.x * w1; acc1[1] += a.y * w1; acc1[2] += a.z * w1; acc1[3] += a.w * w1;
    acc1[4] += c.x * w1; acc1[5] += c.y * w1; acc1[6] += c.z * w1; acc1[7] += c.w * w1;
  }
  float b0 = b[j], b1 = b[j + 64];
#pragma unroll
  for (int q = 0; q < NB; ++q) {
    y[(size_t)(n0 + q) * HDIM + j] = (_Float16)fmaxf(acc0[q] + b0, 0.f);
    y[(size_t)(n0 + q) * HDIM + j + 64] = (_Float16)fmaxf(acc1[q] + b1, 0.f);
  }
}

__device__ __forceinline__ float sigmoidf_(float v) {
  return 1.f / (1.f + expf(-v));
}

// ---------------- MFMA GRU + attention: 32 nodes/block, 4 waves ---------------------------
__global__ __launch_bounds__(256) void gru_mfma(
    const _Float16* __restrict__ Xh, const _Float16* __restrict__ Hp,
    const _Float16* __restrict__ Bt, const float* __restrict__ bcomb,
    const float* __restrict__ Waw, const float* __restrict__ baw,
    _Float16* __restrict__ hout, float* __restrict__ acc,
    float* __restrict__ sden, float* __restrict__ mxv) {
  const int AST = 264;
  __shared__ _Float16 A_lds[32 * AST];
  __shared__ float h_lds[32 * 132];
  __shared__ float lg[32], facs[32], ps[32];
  int tid = threadIdx.x;
  int w = tid >> 6, lane = tid & 63;
  int n0 = blockIdx.x * 32;

#pragma unroll
  for (int i = 0; i < 4; ++i) {
    int cid = tid + i * 256;
    int row = cid >> 5, ch = cid & 31;
    int n = n0 + row;
    v8h v = {(_Float16)0, (_Float16)0, (_Float16)0, (_Float16)0,
             (_Float16)0, (_Float16)0, (_Float16)0, (_Float16)0};
    if (n < NNODES) {
      if (ch < 16) v = *(const v8h*)&Xh[(size_t)n * HDIM + ch * 8];
      else if (Hp) v = *(const v8h*)&Hp[(size_t)n * HDIM + (ch - 16) * 8];
    }
    *(v8h*)&A_lds[row * AST + ch * 8] = v;
  }
  __syncthreads();

  int lj = lane & 15, lr = lane >> 4;
  v4f accf[2][8];
#pragma unroll
  for (int m = 0; m < 2; ++m)
#pragma unroll
    for (int f = 0; f < 8; ++f) accf[m][f] = (v4f){0.f, 0.f, 0.f, 0.f};

  for (int ks = 0; ks < 8; ++ks) {
    v8h a0 = *(const v8h*)&A_lds[lj * AST + ks * 32 + lr * 8];
    v8h a1 = *(const v8h*)&A_lds[(16 + lj) * AST + ks * 32 + lr * 8];
#pragma unroll
    for (int g = 0; g < 4; ++g)
#pragma unroll
      for (int p = 0; p < 2; ++p) {
        int col = (g * 8 + w * 2 + p) * 16 + lj;
        v8h b = *(const v8h*)&Bt[(size_t)col * 256 + ks * 32 + lr * 8];
        accf[0][g * 2 + p] =
            __builtin_amdgcn_mfma_f32_16x16x32_f16(a0, b, accf[0][g * 2 + p], 0, 0, 0);
        accf[1][g * 2 + p] =
            __builtin_amdgcn_mfma_f32_16x16x32_f16(a1, b, accf[1][g * 2 + p], 0, 0, 0);
      }
  }

#pragma unroll
  for (int p = 0; p < 2; ++p) {
    int j = (w * 2 + p) * 16 + lj;
    float br = bcomb[j], bz = bcomb[128 + j], bxn = bcomb[256 + j], bhn = bcomb[384 + j];
#pragma unroll
    for (int m = 0; m < 2; ++m)
#pragma unroll
      for (int reg = 0; reg < 4; ++reg) {
        int row = m * 16 + lr * 4 + reg;
        float r = sigmoidf_(accf[m][0 + p][reg] + br);
        float z = sigmoidf_(accf[m][2 + p][reg] + bz);
        float hp = (float)A_lds[row * AST + 128 + j];
        float nc = tanhf(accf[m][4 + p][reg] + bxn + r * (accf[m][6 + p][reg] + bhn));
        h_lds[row * 132 + j] = (1.f - z) * nc + z * hp;
      }
  }
  __syncthreads();

  float waw0 = Waw[lane], waw1 = Waw[lane + 64];
#pragma unroll
  for (int q = 0; q < 8; ++q) {
    int row = w * 8 + q;
    float v = tanhf(h_lds[row * 132 + lane]) * waw0 +
              tanhf(h_lds[row * 132 + lane + 64]) * waw1;
#pragma unroll
    for (int off = 32; off > 0; off >>= 1) v += __shfl_down(v, off, 64);
    if (lane == 0) lg[row] = v;
  }
  __syncthreads();
  if (tid < 32) {
    int n = n0 + tid;
    if (n < NNODES) {
      float l = lg[tid] + baw[0];
      float m = mxv[n];
      float mnew = fmaxf(m, l);
      float fac = expf(m - mnew);
      float pp = expf(l - mnew);
      facs[tid] = fac;
      ps[tid] = pp;
      sden[n] = sden[n] * fac + pp;
      mxv[n] = mnew;
    }
  }
  __syncthreads();
#pragma unroll
  for (int i = 0; i < 16; ++i) {
    int idx = tid + i * 256;
    int row = idx >> 7, col = idx & 127;
    int n = n0 + row;
    if (n < NNODES) {
      float hv = h_lds[row * 132 + col];
      size_t o = (size_t)n * HDIM + col;
      acc[o] = acc[o] * facs[row] + ps[row] * hv;
      hout[o] = (_Float16)hv;
    }
  }
}

// ---- finalize: out /= s ------------------------------------------------------------------
__global__ __launch_bounds__(256) void attn_finalize(
    float* __restrict__ acc, const float* __restrict__ s) {
  int idx = blockIdx.x * 256 + threadIdx.x;
  if (idx >= NNODES * HDIM) return;
  acc[idx] = acc[idx] / s[idx >> 7];
}

extern "C" void kernel_launch(void* const* d_in, const int* in_sizes, int n_in,
                              void* d_out, int out_size, void* d_ws, size_t ws_size,
                              hipStream_t stream) {
  const float* static_dense = (const float*)d_in[0];
  const int*   static_sparse = (const int*)d_in[1];
  const float* dyn_dense = (const float*)d_in[2];
  const int*   dyn_sparse = (const int*)d_in[3];
  const int*   edges = (const int*)d_in[4];
  const float* weights = (const float*)d_in[5];
  const float* s_emb = (const float*)d_in[6];
  const float* d_emb = (const float*)d_in[7];
  const float* Ws = (const float*)d_in[8];
  const float* bs = (const float*)d_in[9];
  const float* gW1 = (const float*)d_in[10];
  const float* gb1 = (const float*)d_in[11];
  const float* gW2 = (const float*)d_in[12];
  const float* gb2 = (const float*)d_in[13];
  const float* Wx = (const float*)d_in[14];
  const float* Wh = (const float*)d_in[15];
  const float* bx = (const float*)d_in[16];
  const float* bh = (const float*)d_in[17];
  const float* Waw = (const float*)d_in[18];
  const float* baw = (const float*)d_in[19];
  float* out = (float*)d_out;  // attention accumulator [N,128] fp32

  const size_t N = NNODES;
  char* p = (char*)d_ws;
  auto alloc = [&](size_t bytes) { char* r = p; p += (bytes + 255) & ~(size_t)255; return r; };
  float*     sden   = (float*)alloc(N * 4);
  float*     mxv    = (float*)alloc(N * 4);
  _Float16*  hA     = (_Float16*)alloc(N * HDIM * 2);
  _Float16*  hB     = (_Float16*)alloc(N * HDIM * 2);
  _Float16*  dynx   = (_Float16*)alloc(N * G0DIM * 2);
  _Float16*  m1h    = (_Float16*)alloc(N * G0DIM * 2);
  _Float16*  h1h    = (_Float16*)alloc(N * HDIM * 2);
  _Float16*  Xh     = (_Float16*)alloc(N * HDIM * 2);
  float*     Wf32   = (float*)alloc((size_t)TSTEPS * HDIM * H3 * 4);
  _Float16*  Wcombt = (_Float16*)alloc((size_t)TSTEPS * 512 * 256 * 2);
  float*     bfb    = (float*)alloc((size_t)TSTEPS * H3 * 4);
  float*     bcomb  = (float*)alloc((size_t)TSTEPS * 512 * 4);
  int*       deg    = (int*)alloc((size_t)TSTEPS * N * 4);
  int*       offs   = (int*)alloc((size_t)TSTEPS * (N + 1) * 4);
  int*       cursor = (int*)alloc((size_t)TSTEPS * N * 4);
  int*       csum   = (int*)alloc((size_t)TSTEPS * NCH * 4);
  int*       cbase  = (int*)alloc((size_t)TSTEPS * NCH * 4);
  int2*      csr    = (int2*)alloc((size_t)NEDGES * 8);

  // ---- weight/bias preprocessing ----
  fuse_w<<<TSTEPS * HDIM, H3, 0, stream>>>(gW2, Wx, Wf32);
  fuse_b<<<TSTEPS, H3, 0, stream>>>(gb2, Wx, bx, bfb);
  pack_wcomb<<<TSTEPS * 512, 256, 0, stream>>>(Wf32, Wh, Wcombt);
  pack_bcomb<<<TSTEPS, 512, 0, stream>>>(bfb, bh, bcomb);

  // ---- batched CSR offsets for all timesteps (parallel hierarchical scan) ----
  fill_zero_int<<<(TSTEPS * NNODES + 255) / 256, 256, 0, stream>>>(deg, TSTEPS * NNODES);
  hist_all<<<(TSTEPS * NEDGES + 255) / 256, 256, 0, stream>>>(edges, deg);
  scan_k1<<<TSTEPS * NCH, 256, 0, stream>>>(deg, csum);
  scan_k2<<<TSTEPS, 128, 0, stream>>>(csum, cbase, offs);
  scan_k3<<<TSTEPS * NCH, 512, 0, stream>>>(deg, cbase, offs, cursor);

  static_encode_attn_init<<<NNODES, 128, 0, stream>>>(
      static_dense, static_sparse, s_emb, Ws, bs, Waw, baw, out, sden, mxv);

  const int EB = (NEDGES + 255) / 256;
  const int GRUB = (NNODES + 31) / 32;
  for (int t = 0; t < TSTEPS; ++t) {
    const int* e_src = edges + (size_t)t * 2 * NEDGES;
    const int* e_dst = e_src + NEDGES;
    const float* w_t = weights + (size_t)t * NEDGES;
    const int* off_t = offs + (size_t)t * (N + 1);
    _Float16* hcur = (t & 1) ? hB : hA;
    const _Float16* hprev = (t == 0) ? nullptr : ((t & 1) ? hA : hB);

    fill_csr<<<EB, 256, 0, stream>>>(e_src, e_dst, w_t, cursor + (size_t)t * N, csr);

    dynx_gather_h<<<(NNODES * 8 + 255) / 256, 256, 0, stream>>>(
        dyn_dense + (size_t)t * N * DDIM, dyn_sparse + (size_t)t * N * 2, d_emb, dynx);

    gather_agg_h<G0DIM><<<(NNODES + 31) / 32, 256, 0, stream>>>(off_t, csr, dynx, m1h);

    rowmm64<<<NNODES / 8, 64, 0, stream>>>(
        m1h, gW1 + (size_t)t * G0DIM * HDIM, gb1 + (size_t)t * HDIM, h1h);

    gather_agg_h<HDIM><<<(NNODES + 15) / 16, 256, 0, stream>>>(off_t, csr, h1h, Xh);

    gru_mfma<<<GRUB, 256, 0, stream>>>(
        Xh, hprev, Wcombt + (size_t)t * 512 * 256, bcomb + t * 512,
        Waw, baw, hcur, out, sden, mxv);
  }

  attn_finalize<<<(NNODES * HDIM + 255) / 256, 256, 0, stream>>>(out, sden);
}

// Round 9
// 1850.256 us; speedup vs baseline: 10.2296x; 1.1014x over previous
//
#include <hip/hip_runtime.h>
#include <hip/hip_bf16.h>

#define NNODES 50000
#define TSTEPS 8
#define NEDGES 800000
#define VVOCAB 1000
#define DDIM 32
#define HDIM 128
#define G0DIM 64
#define H3 384
#define NCH 98  // ceil(NNODES/512) chunks per timestep

typedef _Float16 v8h __attribute__((ext_vector_type(8)));
typedef float v4f __attribute__((ext_vector_type(4)));

// ---------------- zero fill for int counters ---------------------------------------------
__global__ __launch_bounds__(256) void fill_zero_int(int* __restrict__ p, int n) {
  int i = blockIdx.x * 256 + threadIdx.x;
  if (i < n) p[i] = 0;
}

// ---------------- batched histogram + rank capture (the ONLY global atomics) --------------
__global__ __launch_bounds__(256) void hist_all(const int* __restrict__ edges,
                                                int* __restrict__ deg,
                                                int* __restrict__ rank) {
  int e = blockIdx.x * 256 + threadIdx.x;
  int t = blockIdx.y;
  if (e >= NEDGES) return;
  int dst = edges[(size_t)t * 2 * NEDGES + NEDGES + e];
  rank[(size_t)t * NEDGES + e] = atomicAdd(&deg[t * NNODES + dst], 1);
}

// ---------------- hierarchical scan: K1 chunk sums ----------------------------------------
__global__ __launch_bounds__(256) void scan_k1(const int* __restrict__ deg,
                                               int* __restrict__ csum) {
  int bid = blockIdx.x;  // t*NCH + c
  int t = bid / NCH, c = bid % NCH;
  int tid = threadIdx.x;
  int s = 0;
#pragma unroll
  for (int i = 0; i < 2; ++i) {
    int n = c * 512 + tid + i * 256;
    if (n < NNODES) s += deg[t * NNODES + n];
  }
#pragma unroll
  for (int off = 32; off > 0; off >>= 1) s += __shfl_down(s, off, 64);
  __shared__ int wsum[4];
  if ((tid & 63) == 0) wsum[tid >> 6] = s;
  __syncthreads();
  if (tid == 0) csum[bid] = wsum[0] + wsum[1] + wsum[2] + wsum[3];
}

// ---------------- K2: per-t exclusive scan of 98 chunk sums -------------------------------
__global__ __launch_bounds__(128) void scan_k2(const int* __restrict__ csum,
                                               int* __restrict__ cbase,
                                               int* __restrict__ off) {
  int t = blockIdx.x;
  int tid = threadIdx.x;
  __shared__ int buf[128];
  int own = (tid < NCH) ? csum[t * NCH + tid] : 0;
  buf[tid] = own;
  __syncthreads();
  for (int d = 1; d < 128; d <<= 1) {
    int v = (tid >= d) ? buf[tid - d] : 0;
    __syncthreads();
    buf[tid] += v;
    __syncthreads();
  }
  if (tid < NCH) cbase[t * NCH + tid] = buf[tid] - own;
  if (tid == 0) off[(size_t)t * (NNODES + 1) + NNODES] = NEDGES;
}

// ---------------- K3: in-chunk exclusive scan + base -> off -------------------------------
__global__ __launch_bounds__(512) void scan_k3(const int* __restrict__ deg,
                                               const int* __restrict__ cbase,
                                               int* __restrict__ off) {
  int bid = blockIdx.x;
  int t = bid / NCH, c = bid % NCH;
  int tid = threadIdx.x;
  int n = c * 512 + tid;
  int d = (n < NNODES) ? deg[t * NNODES + n] : 0;
  __shared__ int buf[512];
  buf[tid] = d;
  __syncthreads();
  for (int s = 1; s < 512; s <<= 1) {
    int v = (tid >= s) ? buf[tid - s] : 0;
    __syncthreads();
    buf[tid] += v;
    __syncthreads();
  }
  if (n < NNODES) {
    off[(size_t)t * (NNODES + 1) + n] = cbase[bid] + buf[tid] - d;
  }
}

// ---------------- CSR fill, ALL timesteps, atomic-free (pos = off[dst] + rank) ------------
__global__ __launch_bounds__(256) void fill_csr_all(
    const int* __restrict__ edges, const float* __restrict__ weights,
    const int* __restrict__ rank, const int* __restrict__ offs,
    int2* __restrict__ csr) {
  int e = blockIdx.x * 256 + threadIdx.x;
  int t = blockIdx.y;
  if (e >= NEDGES) return;
  const int* eb = edges + (size_t)t * 2 * NEDGES;
  int dst = eb[NEDGES + e];
  int pos = offs[(size_t)t * (NNODES + 1) + dst] + rank[(size_t)t * NEDGES + e];
  int2 pk;
  pk.x = eb[e];
  pk.y = __float_as_int(weights[(size_t)t * NEDGES + e]);
  csr[(size_t)t * NEDGES + pos] = pk;
}

// ---------------- pull aggregation fp16, D halves/row, 8 halves/lane ----------------------
template <int D>
__global__ __launch_bounds__(256) void gather_agg_h(
    const int* __restrict__ off, const int2* __restrict__ csr,
    const _Float16* __restrict__ x, _Float16* __restrict__ m) {
  const int LPN = D / 8;
  int n = blockIdx.x * (256 / LPN) + threadIdx.x / LPN;
  int l = threadIdx.x % LPN;
  if (n >= NNODES) return;
  int s0 = off[n], s1 = off[n + 1];
  float a0[8], a1[8];
#pragma unroll
  for (int i = 0; i < 8; ++i) { a0[i] = 0.f; a1[i] = 0.f; }
  int e = s0;
  for (; e + 1 < s1; e += 2) {
    int2 eA = csr[e], eB = csr[e + 1];
    v8h xA = *(const v8h*)&x[(size_t)eA.x * D + l * 8];
    v8h xB = *(const v8h*)&x[(size_t)eB.x * D + l * 8];
    float wA = __int_as_float(eA.y), wB = __int_as_float(eB.y);
#pragma unroll
    for (int i = 0; i < 8; ++i) {
      a0[i] += wA * (float)xA[i];
      a1[i] += wB * (float)xB[i];
    }
  }
  if (e < s1) {
    int2 eA = csr[e];
    v8h xA = *(const v8h*)&x[(size_t)eA.x * D + l * 8];
    float wA = __int_as_float(eA.y);
#pragma unroll
    for (int i = 0; i < 8; ++i) a0[i] += wA * (float)xA[i];
  }
  v8h r;
#pragma unroll
  for (int i = 0; i < 8; ++i) r[i] = (_Float16)(a0[i] + a1[i]);
  *(v8h*)&m[(size_t)n * D + l * 8] = r;
}

// ---- fused weight precompute: Wf32[t] = W2_t @ Wx ([128,128]@[128,384]) ------------------
__global__ __launch_bounds__(384) void fuse_w(
    const float* __restrict__ gW2, const float* __restrict__ Wx, float* __restrict__ Wf) {
  int t = blockIdx.x >> 7;
  int k = blockIdx.x & 127;
  int j = threadIdx.x;
  __shared__ float row[HDIM];
  if (j < HDIM) row[j] = gW2[((size_t)t * HDIM + k) * HDIM + j];
  __syncthreads();
  float acc = 0.f;
#pragma unroll 8
  for (int c = 0; c < HDIM; ++c) acc += row[c] * Wx[c * H3 + j];
  Wf[((size_t)t * HDIM + k) * H3 + j] = acc;
}

// ---- fused bias precompute: bf[t] = b2_t @ Wx + bx ---------------------------------------
__global__ __launch_bounds__(384) void fuse_b(
    const float* __restrict__ gb2, const float* __restrict__ Wx,
    const float* __restrict__ bx, float* __restrict__ bf) {
  int t = blockIdx.x;
  int j = threadIdx.x;
  __shared__ float row[HDIM];
  if (j < HDIM) row[j] = gb2[t * HDIM + j];
  __syncthreads();
  float acc = bx[j];
#pragma unroll 8
  for (int c = 0; c < HDIM; ++c) acc += row[c] * Wx[c * H3 + j];
  bf[t * H3 + j] = acc;
}

// ---- pack combined transposed fp16 weights: Wcombt[t][col(512)][k(256)] ------------------
__global__ __launch_bounds__(256) void pack_wcomb(
    const float* __restrict__ Wf32, const float* __restrict__ Wh,
    _Float16* __restrict__ Wcombt) {
  int t = blockIdx.x >> 9;
  int col = blockIdx.x & 511;
  int k = threadIdx.x;  // 0..255
  float v;
  if (col < 384) {
    if (k < 128) v = Wf32[((size_t)t * HDIM + k) * H3 + col];
    else v = (col < 256) ? Wh[(size_t)(k - 128) * H3 + col] : 0.f;
  } else {
    v = (k < 128) ? 0.f : Wh[(size_t)(k - 128) * H3 + (col - 128)];
  }
  Wcombt[((size_t)t * 512 + col) * 256 + k] = (_Float16)v;
}

// ---- pack combined bias: bcomb[t][512] ----------------------------------------------------
__global__ __launch_bounds__(512) void pack_bcomb(
    const float* __restrict__ bfb, const float* __restrict__ bh,
    float* __restrict__ bcomb) {
  int t = blockIdx.x;
  int c = threadIdx.x;
  float v;
  if (c < 256) v = bfb[t * H3 + c] + bh[c];
  else if (c < 384) v = bfb[t * H3 + c];
  else v = bh[c - 128];
  bcomb[t * 512 + c] = v;
}

// ---- static encoder + attention init ------------------------------------------------------
__global__ __launch_bounds__(128) void static_encode_attn_init(
    const float* __restrict__ dense, const int* __restrict__ sparse,
    const float* __restrict__ emb,
    const float* __restrict__ Ws, const float* __restrict__ bs,
    const float* __restrict__ Waw, const float* __restrict__ baw,
    float* __restrict__ acc, float* __restrict__ s, float* __restrict__ mx) {
  int n = blockIdx.x;
  int j = threadIdx.x;
  __shared__ float xs[G0DIM];
  if (j < G0DIM) {
    float v;
    if (j < 16) {
      v = emb[sparse[n * 2 + 0] * 16 + j];
    } else if (j < 32) {
      v = emb[VVOCAB * 16 + sparse[n * 2 + 1] * 16 + (j - 16)];
    } else {
      v = dense[n * DDIM + (j - 32)];
    }
    xs[j] = v;
  }
  __syncthreads();
  float a = bs[j];
#pragma unroll 16
  for (int k = 0; k < G0DIM; ++k) a += xs[k] * Ws[k * HDIM + j];
  a = fmaxf(a, 0.f);
  float v = tanhf(a) * Waw[j];
  __shared__ float red[2];
  int lane = j & 63, wid = j >> 6;
#pragma unroll
  for (int off = 32; off > 0; off >>= 1) v += __shfl_down(v, off, 64);
  if (lane == 0) red[wid] = v;
  __syncthreads();
  acc[(size_t)n * HDIM + j] = a;
  if (j == 0) {
    s[n] = 1.f;
    mx[n] = red[0] + red[1] + baw[0];
  }
}

// ---------------- dynamic feature gather -> fp16, 8 halves/thread -------------------------
__global__ __launch_bounds__(256) void dynx_gather_h(
    const float* __restrict__ dense_t, const int* __restrict__ sparse_t,
    const float* __restrict__ emb, _Float16* __restrict__ xout) {
  int idx = blockIdx.x * 256 + threadIdx.x;  // over N*8
  int n = idx >> 3, k8 = idx & 7;
  if (n >= NNODES) return;
  const float* src;
  if (k8 < 2)
    src = &emb[sparse_t[n * 2 + 0] * 16 + k8 * 8];
  else if (k8 < 4)
    src = &emb[VVOCAB * 16 + sparse_t[n * 2 + 1] * 16 + (k8 - 2) * 8];
  else
    src = &dense_t[n * DDIM + (k8 - 4) * 8];
  float4 f0 = *(const float4*)src;
  float4 f1 = *(const float4*)(src + 4);
  v8h v = {(_Float16)f0.x, (_Float16)f0.y, (_Float16)f0.z, (_Float16)f0.w,
           (_Float16)f1.x, (_Float16)f1.y, (_Float16)f1.z, (_Float16)f1.w};
  *(v8h*)&xout[(size_t)n * G0DIM + k8 * 8] = v;
}

// ---------------- row matmul (fp16 in/out): 64 thr, NB=8 nodes, 2 cols/thread -------------
__global__ __launch_bounds__(64) void rowmm64(
    const _Float16* __restrict__ x, const float* __restrict__ W,
    const float* __restrict__ b, _Float16* __restrict__ y) {
  const int NB = 8;
  int n0 = blockIdx.x * NB;
  int j = threadIdx.x;
  __shared__ float xT[G0DIM][12];
#pragma unroll
  for (int q = 0; q < NB; ++q) xT[j][q] = (float)x[(size_t)(n0 + q) * G0DIM + j];
  __syncthreads();
  float acc0[NB], acc1[NB];
#pragma unroll
  for (int q = 0; q < NB; ++q) { acc0[q] = 0.f; acc1[q] = 0.f; }
#pragma unroll 4
  for (int k = 0; k < G0DIM; ++k) {
    float4 a = *(const float4*)&xT[k][0];
    float4 c = *(const float4*)&xT[k][4];
    float w0 = W[(size_t)k * HDIM + j];
    float w1 = W[(size_t)k * HDIM + j + 64];
    acc0[0] += a.x * w0; acc0[1] += a.y * w0; acc0[2] += a.z * w0; acc0[3] += a.w * w0;
    acc0[4] += c.x * w0; acc0[5] += c.y * w0; acc0[6] += c.z * w0; acc0[7] += c.w * w0;
    acc1[0] += a.x * w1; acc1[1] += a.y * w1; acc1[2] += a.z * w1; acc1[3] += a.w * w1;
    acc1[4] += c.x * w1; acc1[5] += c.y * w1; acc1[6] += c.z * w1; acc1[7] += c.w * w1;
  }
  float b0 = b[j], b1 = b[j + 64];
#pragma unroll
  for (int q = 0; q < NB; ++q) {
    y[(size_t)(n0 + q) * HDIM + j] = (_Float16)fmaxf(acc0[q] + b0, 0.f);
    y[(size_t)(n0 + q) * HDIM + j + 64] = (_Float16)fmaxf(acc1[q] + b1, 0.f);
  }
}

__device__ __forceinline__ float sigmoidf_(float v) {
  return 1.f / (1.f + expf(-v));
}

// ---------------- MFMA GRU + attention: 32 nodes/block, 4 waves ---------------------------
__global__ __launch_bounds__(256) void gru_mfma(
    const _Float16* __restrict__ Xh, const _Float16* __restrict__ Hp,
    const _Float16* __restrict__ Bt, const float* __restrict__ bcomb,
    const float* __restrict__ Waw, const float* __restrict__ baw,
    _Float16* __restrict__ hout, float* __restrict__ acc,
    float* __restrict__ sden, float* __restrict__ mxv) {
  const int AST = 264;
  __shared__ _Float16 A_lds[32 * AST];
  __shared__ float h_lds[32 * 132];
  __shared__ float lg[32], facs[32], ps[32];
  int tid = threadIdx.x;
  int w = tid >> 6, lane = tid & 63;
  int n0 = blockIdx.x * 32;

#pragma unroll
  for (int i = 0; i < 4; ++i) {
    int cid = tid + i * 256;
    int row = cid >> 5, ch = cid & 31;
    int n = n0 + row;
    v8h v = {(_Float16)0, (_Float16)0, (_Float16)0, (_Float16)0,
             (_Float16)0, (_Float16)0, (_Float16)0, (_Float16)0};
    if (n < NNODES) {
      if (ch < 16) v = *(const v8h*)&Xh[(size_t)n * HDIM + ch * 8];
      else if (Hp) v = *(const v8h*)&Hp[(size_t)n * HDIM + (ch - 16) * 8];
    }
    *(v8h*)&A_lds[row * AST + ch * 8] = v;
  }
  __syncthreads();

  int lj = lane & 15, lr = lane >> 4;
  v4f accf[2][8];
#pragma unroll
  for (int m = 0; m < 2; ++m)
#pragma unroll
    for (int f = 0; f < 8; ++f) accf[m][f] = (v4f){0.f, 0.f, 0.f, 0.f};

  for (int ks = 0; ks < 8; ++ks) {
    v8h a0 = *(const v8h*)&A_lds[lj * AST + ks * 32 + lr * 8];
    v8h a1 = *(const v8h*)&A_lds[(16 + lj) * AST + ks * 32 + lr * 8];
#pragma unroll
    for (int g = 0; g < 4; ++g)
#pragma unroll
      for (int p = 0; p < 2; ++p) {
        int col = (g * 8 + w * 2 + p) * 16 + lj;
        v8h b = *(const v8h*)&Bt[(size_t)col * 256 + ks * 32 + lr * 8];
        accf[0][g * 2 + p] =
            __builtin_amdgcn_mfma_f32_16x16x32_f16(a0, b, accf[0][g * 2 + p], 0, 0, 0);
        accf[1][g * 2 + p] =
            __builtin_amdgcn_mfma_f32_16x16x32_f16(a1, b, accf[1][g * 2 + p], 0, 0, 0);
      }
  }

#pragma unroll
  for (int p = 0; p < 2; ++p) {
    int j = (w * 2 + p) * 16 + lj;
    float br = bcomb[j], bz = bcomb[128 + j], bxn = bcomb[256 + j], bhn = bcomb[384 + j];
#pragma unroll
    for (int m = 0; m < 2; ++m)
#pragma unroll
      for (int reg = 0; reg < 4; ++reg) {
        int row = m * 16 + lr * 4 + reg;
        float r = sigmoidf_(accf[m][0 + p][reg] + br);
        float z = sigmoidf_(accf[m][2 + p][reg] + bz);
        float hp = (float)A_lds[row * AST + 128 + j];
        float nc = tanhf(accf[m][4 + p][reg] + bxn + r * (accf[m][6 + p][reg] + bhn));
        h_lds[row * 132 + j] = (1.f - z) * nc + z * hp;
      }
  }
  __syncthreads();

  float waw0 = Waw[lane], waw1 = Waw[lane + 64];
#pragma unroll
  for (int q = 0; q < 8; ++q) {
    int row = w * 8 + q;
    float v = tanhf(h_lds[row * 132 + lane]) * waw0 +
              tanhf(h_lds[row * 132 + lane + 64]) * waw1;
#pragma unroll
    for (int off = 32; off > 0; off >>= 1) v += __shfl_down(v, off, 64);
    if (lane == 0) lg[row] = v;
  }
  __syncthreads();
  if (tid < 32) {
    int n = n0 + tid;
    if (n < NNODES) {
      float l = lg[tid] + baw[0];
      float m = mxv[n];
      float mnew = fmaxf(m, l);
      float fac = expf(m - mnew);
      float pp = expf(l - mnew);
      facs[tid] = fac;
      ps[tid] = pp;
      sden[n] = sden[n] * fac + pp;
      mxv[n] = mnew;
    }
  }
  __syncthreads();
#pragma unroll
  for (int i = 0; i < 16; ++i) {
    int idx = tid + i * 256;
    int row = idx >> 7, col = idx & 127;
    int n = n0 + row;
    if (n < NNODES) {
      float hv = h_lds[row * 132 + col];
      size_t o = (size_t)n * HDIM + col;
      acc[o] = acc[o] * facs[row] + ps[row] * hv;
      hout[o] = (_Float16)hv;
    }
  }
}

// ---- finalize: out /= s ------------------------------------------------------------------
__global__ __launch_bounds__(256) void attn_finalize(
    float* __restrict__ acc, const float* __restrict__ s) {
  int idx = blockIdx.x * 256 + threadIdx.x;
  if (idx >= NNODES * HDIM) return;
  acc[idx] = acc[idx] / s[idx >> 7];
}

extern "C" void kernel_launch(void* const* d_in, const int* in_sizes, int n_in,
                              void* d_out, int out_size, void* d_ws, size_t ws_size,
                              hipStream_t stream) {
  const float* static_dense = (const float*)d_in[0];
  const int*   static_sparse = (const int*)d_in[1];
  const float* dyn_dense = (const float*)d_in[2];
  const int*   dyn_sparse = (const int*)d_in[3];
  const int*   edges = (const int*)d_in[4];
  const float* weights = (const float*)d_in[5];
  const float* s_emb = (const float*)d_in[6];
  const float* d_emb = (const float*)d_in[7];
  const float* Ws = (const float*)d_in[8];
  const float* bs = (const float*)d_in[9];
  const float* gW1 = (const float*)d_in[10];
  const float* gb1 = (const float*)d_in[11];
  const float* gW2 = (const float*)d_in[12];
  const float* gb2 = (const float*)d_in[13];
  const float* Wx = (const float*)d_in[14];
  const float* Wh = (const float*)d_in[15];
  const float* bx = (const float*)d_in[16];
  const float* bh = (const float*)d_in[17];
  const float* Waw = (const float*)d_in[18];
  const float* baw = (const float*)d_in[19];
  float* out = (float*)d_out;  // attention accumulator [N,128] fp32

  const size_t N = NNODES;
  char* p = (char*)d_ws;
  auto alloc = [&](size_t bytes) { char* r = p; p += (bytes + 255) & ~(size_t)255; return r; };
  float*     sden   = (float*)alloc(N * 4);
  float*     mxv    = (float*)alloc(N * 4);
  _Float16*  hA     = (_Float16*)alloc(N * HDIM * 2);
  _Float16*  hB     = (_Float16*)alloc(N * HDIM * 2);
  _Float16*  dynx   = (_Float16*)alloc(N * G0DIM * 2);
  _Float16*  m1h    = (_Float16*)alloc(N * G0DIM * 2);
  // rank (8*800000*4 = 25.6MB) aliases [h1h|Xh] (2*N*128*2 = 25.6MB):
  // rank is fully consumed by fill_csr_all BEFORE the loop's first rowmm64 write (stream order).
  char*      ralias = alloc((size_t)TSTEPS * NEDGES * 4);
  int*       rank   = (int*)ralias;
  _Float16*  h1h    = (_Float16*)ralias;
  _Float16*  Xh     = h1h + N * HDIM;
  float*     Wf32   = (float*)alloc((size_t)TSTEPS * HDIM * H3 * 4);
  _Float16*  Wcombt = (_Float16*)alloc((size_t)TSTEPS * 512 * 256 * 2);
  float*     bfb    = (float*)alloc((size_t)TSTEPS * H3 * 4);
  float*     bcomb  = (float*)alloc((size_t)TSTEPS * 512 * 4);
  int*       deg    = (int*)alloc((size_t)TSTEPS * N * 4);
  int*       offs   = (int*)alloc((size_t)TSTEPS * (N + 1) * 4);
  int*       csum   = (int*)alloc((size_t)TSTEPS * NCH * 4);
  int*       cbase  = (int*)alloc((size_t)TSTEPS * NCH * 4);
  int2*      csr    = (int2*)alloc((size_t)TSTEPS * NEDGES * 8);  // all-t CSR, 51.2MB

  const int EB = (NEDGES + 255) / 256;

  // ---- batched CSR for all timesteps: hist(+rank) -> scan -> atomic-free fill ----
  fill_zero_int<<<(TSTEPS * NNODES + 255) / 256, 256, 0, stream>>>(deg, TSTEPS * NNODES);
  hist_all<<<dim3(EB, TSTEPS), 256, 0, stream>>>(edges, deg, rank);
  scan_k1<<<TSTEPS * NCH, 256, 0, stream>>>(deg, csum);
  scan_k2<<<TSTEPS, 128, 0, stream>>>(csum, cbase, offs);
  scan_k3<<<TSTEPS * NCH, 512, 0, stream>>>(deg, cbase, offs);
  fill_csr_all<<<dim3(EB, TSTEPS), 256, 0, stream>>>(edges, weights, rank, offs, csr);

  // ---- weight/bias preprocessing ----
  fuse_w<<<TSTEPS * HDIM, H3, 0, stream>>>(gW2, Wx, Wf32);
  fuse_b<<<TSTEPS, H3, 0, stream>>>(gb2, Wx, bx, bfb);
  pack_wcomb<<<TSTEPS * 512, 256, 0, stream>>>(Wf32, Wh, Wcombt);
  pack_bcomb<<<TSTEPS, 512, 0, stream>>>(bfb, bh, bcomb);

  static_encode_attn_init<<<NNODES, 128, 0, stream>>>(
      static_dense, static_sparse, s_emb, Ws, bs, Waw, baw, out, sden, mxv);

  const int GRUB = (NNODES + 31) / 32;
  for (int t = 0; t < TSTEPS; ++t) {
    const int* off_t = offs + (size_t)t * (N + 1);
    const int2* csr_t = csr + (size_t)t * NEDGES;
    _Float16* hcur = (t & 1) ? hB : hA;
    const _Float16* hprev = (t == 0) ? nullptr : ((t & 1) ? hA : hB);

    dynx_gather_h<<<(NNODES * 8 + 255) / 256, 256, 0, stream>>>(
        dyn_dense + (size_t)t * N * DDIM, dyn_sparse + (size_t)t * N * 2, d_emb, dynx);

    gather_agg_h<G0DIM><<<(NNODES + 31) / 32, 256, 0, stream>>>(off_t, csr_t, dynx, m1h);

    rowmm64<<<NNODES / 8, 64, 0, stream>>>(
        m1h, gW1 + (size_t)t * G0DIM * HDIM, gb1 + (size_t)t * HDIM, h1h);

    gather_agg_h<HDIM><<<(NNODES + 15) / 16, 256, 0, stream>>>(off_t, csr_t, h1h, Xh);

    gru_mfma<<<GRUB, 256, 0, stream>>>(
        Xh, hprev, Wcombt + (size_t)t * 512 * 256, bcomb + t * 512,
        Waw, baw, hcur, out, sden, mxv);
  }

  attn_finalize<<<(NNODES * HDIM + 255) / 256, 256, 0, stream>>>(out, sden);
}